// Round 8
// baseline (1080.890 us; speedup 1.0000x reference)
//
#include <hip/hip_runtime.h>
#include <math.h>

#define N_NODES 50000
#define E_EDGES 500000
#define HDIM    128
#define OUTC    2
#define NGRAPH  512

typedef _Float16 f16x8 __attribute__((ext_vector_type(8)));
typedef float    f32x4 __attribute__((ext_vector_type(4)));

// ---------------- edge histogram over dst + fused weight split-transpose ---
__global__ void k_hist(const int* __restrict__ d0, const int* __restrict__ d1,
                       int ecnt, int off1, int* __restrict__ cnt,
                       const float* __restrict__ W1, const float* __restrict__ W2,
                       _Float16* __restrict__ w1hi, _Float16* __restrict__ w1lo,
                       _Float16* __restrict__ w2hi, _Float16* __restrict__ w2lo) {
    int i = blockIdx.x * blockDim.x + threadIdx.x;
    int stride = gridDim.x * blockDim.x;
    for (int j = i; j < 128 * 128; j += stride) {
        int n = j >> 7, k = j & 127;
        float v = W1[k * 128 + n];
        _Float16 h = (_Float16)v;
        w1hi[j] = h; w1lo[j] = (_Float16)(v - (float)h);
        v = W2[k * 128 + n];
        h = (_Float16)v;
        w2hi[j] = h; w2lo[j] = (_Float16)(v - (float)h);
    }
    for (int j = i; j < ecnt; j += stride) {
        int d = (j < E_EDGES) ? d0[j] : d1[j - E_EDGES] + off1;
        atomicAdd(&cnt[d], 1);
    }
}

// ---------------- scan stage A ---------------------------------------------
__global__ void k_scan_a(const int* __restrict__ cnt, int* __restrict__ excl,
                         int* __restrict__ blksum, float* __restrict__ dinv,
                         const int* __restrict__ bt0, const int* __restrict__ bt1,
                         int goff0, int nn, int nside, float* __restrict__ cnt_g) {
    __shared__ int s[512];
    int t = threadIdx.x;
    int i = blockIdx.x * 512 + t;
    int v = 0;
    if (i < nn) {
        v = cnt[i];
        dinv[i] = 1.0f / sqrtf((float)(v + 1));
        int g = (i < nside) ? bt0[i] + goff0 : bt1[i - nside] + NGRAPH;
        atomicAdd(&cnt_g[g], 1.0f);
    }
    s[t] = v; __syncthreads();
    for (int off = 1; off < 512; off <<= 1) {
        int add = (t >= off) ? s[t - off] : 0;
        __syncthreads();
        s[t] += add;
        __syncthreads();
    }
    if (i < nn) excl[i] = s[t] - v;
    if (t == 511) blksum[blockIdx.x] = s[511];
}

// ---------------- scan stage B ---------------------------------------------
__global__ void k_scan_b(int* __restrict__ blksum, int nb) {
    __shared__ int s[512];
    int t = threadIdx.x;
    int v = (t < nb) ? blksum[t] : 0;
    s[t] = v; __syncthreads();
    for (int off = 1; off < 512; off <<= 1) {
        int add = (t >= off) ? s[t - off] : 0;
        __syncthreads();
        s[t] += add;
        __syncthreads();
    }
    if (t < nb) blksum[t] = s[t] - v;
}

// ---------------- scan stage C: finalize row_ptr AND init fill cursor ------
__global__ void k_scan_c(int* __restrict__ excl, const int* __restrict__ blksum,
                         int* __restrict__ cursor, int nn, int tot) {
    int t = threadIdx.x;
    int i = blockIdx.x * 512 + t;
    if (i < nn) {
        int v = excl[i] + blksum[blockIdx.x];
        excl[i] = v;
        cursor[i] = v;
    }
    if (i == 0) excl[nn] = tot;
}

// ---------------- CSR fill: (src, weight) + graph-of-dst, grouped by dst ---
__global__ void k_fill(const int* __restrict__ s0, const int* __restrict__ s1,
                       const int* __restrict__ d0, const int* __restrict__ d1,
                       int ecnt, int off1, int goff0,
                       const int* __restrict__ bt0, const int* __restrict__ bt1,
                       int* __restrict__ cursor,
                       const float* __restrict__ dinv, int2* __restrict__ edges,
                       int* __restrict__ gdst) {
    int i = blockIdx.x * blockDim.x + threadIdx.x;
    int stride = gridDim.x * blockDim.x;
    for (; i < ecnt; i += stride) {
        int d, sg, g;
        if (i < E_EDGES) {
            int dl = d0[i];
            sg = s0[i]; d = dl; g = bt0[dl] + goff0;
        } else {
            int dl = d1[i - E_EDGES];
            sg = s1[i - E_EDGES] + off1; d = dl + off1; g = bt1[dl] + NGRAPH;
        }
        int p = atomicAdd(&cursor[d], 1);
        float w = dinv[sg] * dinv[d];
        edges[p] = make_int2(sg, __float_as_int(w));
        gdst[p] = g;
    }
}

__device__ inline void cvt8(const float4& p, const float4& q, f16x8& h, f16x8& l) {
    float v[8] = {p.x, p.y, p.z, p.w, q.x, q.y, q.z, q.w};
#pragma unroll
    for (int i = 0; i < 8; i++) {
        _Float16 hh = (_Float16)v[i];
        h[i] = hh;
        l[i] = (_Float16)(v[i] - (float)hh);
    }
}

// ---------------- MFMA split-f16 GEMM: C(f32, Mx128) = A @ W ---------------
template <int ASRC>
__global__ __launch_bounds__(256) void k_gemm_split(
        const float* __restrict__ A0f, const float* __restrict__ A1f, int nside,
        const _Float16* __restrict__ Ahi, const _Float16* __restrict__ Alo,
        const _Float16* __restrict__ Bhi, const _Float16* __restrict__ Blo,
        float* __restrict__ C, int M) {
    __shared__ _Float16 sA[2][128][40];
    __shared__ _Float16 sB[2][128][40];
    int tid = threadIdx.x;
    int wave = tid >> 6, lane = tid & 63;
    int wm = (wave >> 1) * 64;
    int wn = (wave & 1) * 64;
    int quad = lane >> 4, fm = lane & 15;
    int row0 = blockIdx.x * 128;

    int lr = tid >> 2;
    int lk = (tid & 3) * 8;

    f32x4 acc[4][4] = {};
    const float4 z4 = make_float4(0.f, 0.f, 0.f, 0.f);

    for (int kc = 0; kc < 128; kc += 32) {
        int r1 = row0 + lr, r2 = row0 + lr + 64;
        bool ok1 = r1 < M, ok2 = r2 < M;
        f16x8 ah1, al1, ah2, al2;
        if (ASRC == 1) {
            const float* p1 = (r1 < nside) ? A0f + (size_t)r1 * 128
                                           : A1f + (size_t)(r1 - nside) * 128;
            const float* p2 = (r2 < nside) ? A0f + (size_t)r2 * 128
                                           : A1f + (size_t)(r2 - nside) * 128;
            float4 a = ok1 ? *(const float4*)(p1 + kc + lk) : z4;
            float4 b = ok1 ? *(const float4*)(p1 + kc + lk + 4) : z4;
            float4 c = ok2 ? *(const float4*)(p2 + kc + lk) : z4;
            float4 d = ok2 ? *(const float4*)(p2 + kc + lk + 4) : z4;
            cvt8(a, b, ah1, al1);
            cvt8(c, d, ah2, al2);
        } else {
            const f16x8 zf = {};
            ah1 = ok1 ? *(const f16x8*)(Ahi + (size_t)r1 * 128 + kc + lk) : zf;
            al1 = ok1 ? *(const f16x8*)(Alo + (size_t)r1 * 128 + kc + lk) : zf;
            ah2 = ok2 ? *(const f16x8*)(Ahi + (size_t)r2 * 128 + kc + lk) : zf;
            al2 = ok2 ? *(const f16x8*)(Alo + (size_t)r2 * 128 + kc + lk) : zf;
        }
        f16x8 bh1 = *(const f16x8*)(Bhi + (size_t)lr * 128 + kc + lk);
        f16x8 bl1 = *(const f16x8*)(Blo + (size_t)lr * 128 + kc + lk);
        f16x8 bh2 = *(const f16x8*)(Bhi + (size_t)(lr + 64) * 128 + kc + lk);
        f16x8 bl2 = *(const f16x8*)(Blo + (size_t)(lr + 64) * 128 + kc + lk);
        __syncthreads();
        *(f16x8*)&sA[0][lr][lk]      = ah1;
        *(f16x8*)&sA[1][lr][lk]      = al1;
        *(f16x8*)&sA[0][lr + 64][lk] = ah2;
        *(f16x8*)&sA[1][lr + 64][lk] = al2;
        *(f16x8*)&sB[0][lr][lk]      = bh1;
        *(f16x8*)&sB[1][lr][lk]      = bl1;
        *(f16x8*)&sB[0][lr + 64][lk] = bh2;
        *(f16x8*)&sB[1][lr + 64][lk] = bl2;
        __syncthreads();

        f16x8 afh[4], afl[4], bfh[4], bfl[4];
#pragma unroll
        for (int mi = 0; mi < 4; mi++) {
            afh[mi] = *(const f16x8*)&sA[0][wm + mi * 16 + fm][quad * 8];
            afl[mi] = *(const f16x8*)&sA[1][wm + mi * 16 + fm][quad * 8];
        }
#pragma unroll
        for (int ni = 0; ni < 4; ni++) {
            bfh[ni] = *(const f16x8*)&sB[0][wn + ni * 16 + fm][quad * 8];
            bfl[ni] = *(const f16x8*)&sB[1][wn + ni * 16 + fm][quad * 8];
        }
#pragma unroll
        for (int mi = 0; mi < 4; mi++)
#pragma unroll
            for (int ni = 0; ni < 4; ni++) {
                acc[mi][ni] = __builtin_amdgcn_mfma_f32_16x16x32_f16(afh[mi], bfh[ni], acc[mi][ni], 0, 0, 0);
                acc[mi][ni] = __builtin_amdgcn_mfma_f32_16x16x32_f16(afh[mi], bfl[ni], acc[mi][ni], 0, 0, 0);
                acc[mi][ni] = __builtin_amdgcn_mfma_f32_16x16x32_f16(afl[mi], bfh[ni], acc[mi][ni], 0, 0, 0);
            }
    }

#pragma unroll
    for (int mi = 0; mi < 4; mi++)
#pragma unroll
        for (int reg = 0; reg < 4; reg++) {
            int r = row0 + wm + mi * 16 + quad * 4 + reg;
            if (r >= M) continue;
#pragma unroll
            for (int ni = 0; ni < 4; ni++)
                C[(size_t)r * 128 + wn + ni * 16 + fm] = acc[mi][ni][reg];
        }
}

// ---------------- generic fp32 GEMM (head GEMMs) ---------------------------
__global__ __launch_bounds__(256) void k_gemm(
        const float* __restrict__ A, const float* __restrict__ B,
        const float* __restrict__ bias, float* __restrict__ C,
        int M, int Nn, int K, int ldc, int act) {
    __shared__ float As[16][64];
    __shared__ float Bs[16][68];
    int tid = threadIdx.x;
    int tx = tid & 15, ty = tid >> 4;
    int row0 = blockIdx.x * 64, col0 = blockIdx.y * 64;
    float acc[4][4] = {};
    int arow = tid >> 2;
    int acol = (tid & 3) * 4;
    int brow = tid >> 4;
    int bcol = (tid & 15) * 4;

    for (int k0 = 0; k0 < K; k0 += 16) {
        float4 av = make_float4(0.f, 0.f, 0.f, 0.f);
        int ar = row0 + arow;
        if (ar < M) av = *(const float4*)(A + (size_t)ar * K + k0 + acol);
        As[acol + 0][arow] = av.x;
        As[acol + 1][arow] = av.y;
        As[acol + 2][arow] = av.z;
        As[acol + 3][arow] = av.w;

        float4 bv = make_float4(0.f, 0.f, 0.f, 0.f);
        const float* Brow = B + (size_t)(k0 + brow) * Nn;
        int bc = col0 + bcol;
        if (bc + 3 < Nn) {
            bv = *(const float4*)(Brow + bc);
        } else {
            if (bc     < Nn) bv.x = Brow[bc];
            if (bc + 1 < Nn) bv.y = Brow[bc + 1];
            if (bc + 2 < Nn) bv.z = Brow[bc + 2];
        }
        Bs[brow][bcol + 0] = bv.x;
        Bs[brow][bcol + 1] = bv.y;
        Bs[brow][bcol + 2] = bv.z;
        Bs[brow][bcol + 3] = bv.w;
        __syncthreads();

#pragma unroll
        for (int k = 0; k < 16; k++) {
            float4 a = *(const float4*)&As[k][ty * 4];
            float4 b = *(const float4*)&Bs[k][tx * 4];
            acc[0][0] += a.x * b.x; acc[0][1] += a.x * b.y; acc[0][2] += a.x * b.z; acc[0][3] += a.x * b.w;
            acc[1][0] += a.y * b.x; acc[1][1] += a.y * b.y; acc[1][2] += a.y * b.z; acc[1][3] += a.y * b.w;
            acc[2][0] += a.z * b.x; acc[2][1] += a.z * b.y; acc[2][2] += a.z * b.z; acc[2][3] += a.z * b.w;
            acc[3][0] += a.w * b.x; acc[3][1] += a.w * b.y; acc[3][2] += a.w * b.z; acc[3][3] += a.w * b.w;
        }
        __syncthreads();
    }

#pragma unroll
    for (int i = 0; i < 4; i++) {
        int r = row0 + ty * 4 + i;
        if (r >= M) continue;
#pragma unroll
        for (int j = 0; j < 4; j++) {
            int c = col0 + tx * 4 + j;
            if (c >= Nn) continue;
            float v = acc[i][j];
            if (bias) v += bias[c];
            if (act) v = fmaxf(v, 0.0f);
            C[(size_t)r * ldc + c] = v;
        }
    }
}

// ---------------- pool GEMM: zcat[g, side*128+c] = (pool/cnt) @ W3 + b3 ----
__global__ __launch_bounds__(256) void k_gemm_pool(
        const float* __restrict__ pool, const float* __restrict__ cnt_g,
        const float* __restrict__ W, const float* __restrict__ bias,
        float* __restrict__ zcat) {
    __shared__ float As[16][64];
    __shared__ float Bs[16][68];
    int side = blockIdx.z;
    const float* A = pool + (size_t)side * NGRAPH * HDIM;
    const float* cg = cnt_g + side * NGRAPH;
    int tid = threadIdx.x;
    int tx = tid & 15, ty = tid >> 4;
    int row0 = blockIdx.x * 64, col0 = blockIdx.y * 64;
    float acc[4][4] = {};
    int arow = tid >> 2;
    int acol = (tid & 3) * 4;
    int brow = tid >> 4;
    int bcol = (tid & 15) * 4;

    for (int k0 = 0; k0 < 128; k0 += 16) {
        int ar = row0 + arow;
        float sc = 1.0f / fmaxf(cg[ar], 1.0f);
        float4 av = *(const float4*)(A + (size_t)ar * 128 + k0 + acol);
        As[acol + 0][arow] = av.x * sc;
        As[acol + 1][arow] = av.y * sc;
        As[acol + 2][arow] = av.z * sc;
        As[acol + 3][arow] = av.w * sc;

        float4 bv = *(const float4*)(W + (size_t)(k0 + brow) * 128 + col0 + bcol);
        Bs[brow][bcol + 0] = bv.x;
        Bs[brow][bcol + 1] = bv.y;
        Bs[brow][bcol + 2] = bv.z;
        Bs[brow][bcol + 3] = bv.w;
        __syncthreads();

#pragma unroll
        for (int k = 0; k < 16; k++) {
            float4 a = *(const float4*)&As[k][ty * 4];
            float4 b = *(const float4*)&Bs[k][tx * 4];
            acc[0][0] += a.x * b.x; acc[0][1] += a.x * b.y; acc[0][2] += a.x * b.z; acc[0][3] += a.x * b.w;
            acc[1][0] += a.y * b.x; acc[1][1] += a.y * b.y; acc[1][2] += a.y * b.z; acc[1][3] += a.y * b.w;
            acc[2][0] += a.z * b.x; acc[2][1] += a.z * b.y; acc[2][2] += a.z * b.z; acc[2][3] += a.z * b.w;
            acc[3][0] += a.w * b.x; acc[3][1] += a.w * b.y; acc[3][2] += a.w * b.z; acc[3][3] += a.w * b.w;
        }
        __syncthreads();
    }

#pragma unroll
    for (int i = 0; i < 4; i++) {
        int r = row0 + ty * 4 + i;
#pragma unroll
        for (int j = 0; j < 4; j++) {
            int c = col0 + tx * 4 + j;
            zcat[(size_t)r * 256 + side * 128 + c] = acc[i][j] + bias[c];
        }
    }
}

// ---------------- per-node CSR aggregation (layers 1,2) --------------------
// Half-wave x dwordx4: lanes 0-31 handle even edge slots, 32-63 odd; each
// 16-edge group issues 8 independent 1KB-equivalent gathers (2 edges/instr).
// Edge records are wave-uniform (SGPR); per-half select via cndmask.
template <int PACK>
__global__ __launch_bounds__(256) void k_agg(
        const float* __restrict__ H, const float* __restrict__ dinv,
        const int* __restrict__ row_ptr, const int2* __restrict__ edges,
        const float* __restrict__ bias,
        _Float16* __restrict__ outHi, _Float16* __restrict__ outLo,
        float* __restrict__ outF, int nnodes) {
    int wave = threadIdx.x >> 6, lane = threadIdx.x & 63;
    int half = lane >> 5, li = lane & 31;
    int node = blockIdx.x * 4 + wave;
    if (node >= nnodes) return;

    float di = dinv[node];
    float4 hv = ((const float4*)(H + (size_t)node * HDIM))[li];
    float wself = half ? 0.f : di * di;   // half 1 contributes 0 (dup load cached)
    float4 acc;
    acc.x = hv.x * wself; acc.y = hv.y * wself;
    acc.z = hv.z * wself; acc.w = hv.w * wself;

    int rs = __builtin_amdgcn_readfirstlane(row_ptr[node]);
    int re = __builtin_amdgcn_readfirstlane(row_ptr[node + 1]);

    for (int base = rs; base < re; base += 16) {
        int nrem = re - base, m = nrem - 1;
        int2 R[16];
#pragma unroll
        for (int j = 0; j < 16; j++)
            R[j] = edges[base + (j < nrem ? j : m)];   // uniform -> scalar loads
#pragma unroll
        for (int j = 0; j < 8; j++) {
            int srcj = half ? R[2 * j + 1].x : R[2 * j].x;
            int wbit = half ? R[2 * j + 1].y : R[2 * j].y;
            float wj = (2 * j + half) < nrem ? __int_as_float(wbit) : 0.f;
            float4 v = ((const float4*)(H + (size_t)srcj * HDIM))[li];
            acc.x = fmaf(v.x, wj, acc.x);
            acc.y = fmaf(v.y, wj, acc.y);
            acc.z = fmaf(v.z, wj, acc.z);
            acc.w = fmaf(v.w, wj, acc.w);
        }
    }

    acc.x += __shfl_xor(acc.x, 32);
    acc.y += __shfl_xor(acc.y, 32);
    acc.z += __shfl_xor(acc.z, 32);
    acc.w += __shfl_xor(acc.w, 32);

    if (half == 0) {
        float4 b = ((const float4*)bias)[li];
        float o0 = fmaxf(acc.x + b.x, 0.f);
        float o1 = fmaxf(acc.y + b.y, 0.f);
        float o2 = fmaxf(acc.z + b.z, 0.f);
        float o3 = fmaxf(acc.w + b.w, 0.f);
        if (PACK) {
            float o[4] = {o0, o1, o2, o3};
            union { _Float16 h[4]; uint2 u; } ph, pl;
#pragma unroll
            for (int i = 0; i < 4; i++) {
                _Float16 hh = (_Float16)o[i];
                ph.h[i] = hh;
                pl.h[i] = (_Float16)(o[i] - (float)hh);
            }
            ((uint2*)(outHi + (size_t)node * HDIM))[li] = ph.u;
            ((uint2*)(outLo + (size_t)node * HDIM))[li] = pl.u;
        } else {
            ((float4*)(outF + (size_t)node * HDIM))[li] = make_float4(o0, o1, o2, o3);
        }
    }
}

// ---------------- layer-3 pooled aggregation: linear edge sweep ------------
// gdst[] globally non-decreasing (deterministic scan). A 64-edge chunk is
// single-graph iff gdst[e0]==gdst[e1-1] (~94% of chunks) -> branch-free
// dwordx4 half-wave path, one flush. Boundary chunks walk per-edge.
__global__ __launch_bounds__(256) void k_sweep3(
        const float* __restrict__ H, const int2* __restrict__ edges,
        const int* __restrict__ gdst, const float* __restrict__ dinv,
        const int* __restrict__ bt0, const int* __restrict__ bt1,
        int goff0, int nnodes, int nside, int nedges,
        float* __restrict__ pool) {
    int lane = threadIdx.x & 63;
    int half = lane >> 5, li = lane & 31;
    int wid = blockIdx.x * 4 + (threadIdx.x >> 6);
    int ewaves = (nedges + 63) >> 6;

    if (wid < ewaves) {
        int e0 = wid << 6;
        int e1 = e0 + 64; if (e1 > nedges) e1 = nedges;
        int gfirst = __builtin_amdgcn_readfirstlane(gdst[e0]);
        int glast  = __builtin_amdgcn_readfirstlane(gdst[e1 - 1]);
        float4 acc = make_float4(0.f, 0.f, 0.f, 0.f);

        if (gfirst == glast) {
            for (int base = e0; base < e1; base += 16) {
                int nrem = e1 - base, m = nrem - 1;
                int2 R[16];
#pragma unroll
                for (int j = 0; j < 16; j++)
                    R[j] = edges[base + (j < nrem ? j : m)];
#pragma unroll
                for (int j = 0; j < 8; j++) {
                    int srcj = half ? R[2 * j + 1].x : R[2 * j].x;
                    int wbit = half ? R[2 * j + 1].y : R[2 * j].y;
                    float wj = (2 * j + half) < nrem ? __int_as_float(wbit) : 0.f;
                    float4 v = ((const float4*)(H + (size_t)srcj * HDIM))[li];
                    acc.x = fmaf(v.x, wj, acc.x);
                    acc.y = fmaf(v.y, wj, acc.y);
                    acc.z = fmaf(v.z, wj, acc.z);
                    acc.w = fmaf(v.w, wj, acc.w);
                }
            }
            float* p = pool + (size_t)gfirst * HDIM + li * 4;
            atomicAdd(p + 0, acc.x); atomicAdd(p + 1, acc.y);
            atomicAdd(p + 2, acc.z); atomicAdd(p + 3, acc.w);
        } else {
            int gcur = gfirst;
            for (int e = e0; e < e1; e++) {
                int2 E = edges[e];                                   // uniform
                int g = __builtin_amdgcn_readfirstlane(gdst[e]);
                if (g != gcur) {
                    float* p = pool + (size_t)gcur * HDIM + li * 4;
                    atomicAdd(p + 0, acc.x); atomicAdd(p + 1, acc.y);
                    atomicAdd(p + 2, acc.z); atomicAdd(p + 3, acc.w);
                    acc = make_float4(0.f, 0.f, 0.f, 0.f);
                    gcur = g;
                }
                float wj = half ? 0.f : __int_as_float(E.y);
                float4 v = ((const float4*)(H + (size_t)E.x * HDIM))[li];
                acc.x = fmaf(v.x, wj, acc.x);
                acc.y = fmaf(v.y, wj, acc.y);
                acc.z = fmaf(v.z, wj, acc.z);
                acc.w = fmaf(v.w, wj, acc.w);
            }
            float* p = pool + (size_t)gcur * HDIM + li * 4;
            atomicAdd(p + 0, acc.x); atomicAdd(p + 1, acc.y);
            atomicAdd(p + 2, acc.z); atomicAdd(p + 3, acc.w);
        }
    } else {
        // self-loop streaming sweep (float2 per 64-lane mapping)
        int wid2 = wid - ewaves;
        int n0 = wid2 << 6;
        if (n0 >= nnodes) return;
        int n1 = n0 + 64; if (n1 > nnodes) n1 = nnodes;
        float ax = 0.f, ay = 0.f;
        int gcur = (n0 < nside) ? bt0[n0] + goff0 : bt1[n0 - nside] + NGRAPH;
        gcur = __builtin_amdgcn_readfirstlane(gcur);
        for (int n = n0; n < n1; n++) {
            int g = (n < nside) ? bt0[n] + goff0 : bt1[n - nside] + NGRAPH;
            g = __builtin_amdgcn_readfirstlane(g);
            float dn = dinv[n];
            float w = dn * dn;
            float2 v = ((const float2*)(H + (size_t)n * HDIM))[lane];
            if (g != gcur) {
                float* p = pool + (size_t)gcur * HDIM + lane * 2;
                atomicAdd(p, ax); atomicAdd(p + 1, ay);
                ax = 0.f; ay = 0.f;
                gcur = g;
            }
            ax = fmaf(v.x, w, ax);
            ay = fmaf(v.y, w, ay);
        }
        float* p = pool + (size_t)gcur * HDIM + lane * 2;
        atomicAdd(p, ax); atomicAdd(p + 1, ay);
    }
}

extern "C" void kernel_launch(void* const* d_in, const int* in_sizes, int n_in,
                              void* d_out, int out_size, void* d_ws, size_t ws_size,
                              hipStream_t stream) {
    (void)in_sizes; (void)n_in; (void)out_size;

    const float* x[2]  = {(const float*)d_in[0], (const float*)d_in[1]};
    const int*   ei[2] = {(const int*)d_in[2], (const int*)d_in[3]};
    const int*   bt[2] = {(const int*)d_in[4], (const int*)d_in[5]};
    const float* W1  = (const float*)d_in[6];  const float* b1  = (const float*)d_in[7];
    const float* W2  = (const float*)d_in[8];  const float* b2  = (const float*)d_in[9];
    const float* W3  = (const float*)d_in[10]; const float* b3  = (const float*)d_in[11];
    const float* Wc1 = (const float*)d_in[12]; const float* bc1 = (const float*)d_in[13];
    const float* Wc2 = (const float*)d_in[14]; const float* bc2 = (const float*)d_in[15];
    const float* Wc3 = (const float*)d_in[16]; const float* bc3 = (const float*)d_in[17];
    float* out = (float*)d_out;

    const bool batched = ws_size >= 120ull * 1000 * 1000;
    const int NN = batched ? 2 * N_NODES : N_NODES;
    const int NE = batched ? 2 * E_EDGES : E_EDGES;

    char* ws = (char*)d_ws;
    size_t off = 0;
    auto carve = [&](size_t bytes) -> char* {
        char* p = ws + off;
        off += (bytes + 255) & ~(size_t)255;
        return p;
    };

    int*   edge_cnt = (int*)  carve((size_t)NN * 4);
    int*   cursor   = (int*)  carve((size_t)NN * 4);
    float* pool_s   = (float*)carve((size_t)2 * NGRAPH * HDIM * 4);
    float* cnt_g    = (float*)carve((size_t)2 * NGRAPH * 4);
    float* dinv     = (float*)carve((size_t)NN * 4);
    int*   row_ptr  = (int*)  carve((size_t)(NN + 1) * 4);
    int2*  edges    = (int2*) carve((size_t)NE * 8);
    int*   gdst     = (int*)  carve((size_t)NE * 4);
    int*   blksum   = (int*)  carve(1024 * 4);
    _Float16* wt    = (_Float16*)carve(4 * 128 * 128 * 2);
    _Float16* hS    = (_Float16*)carve((size_t)NN * HDIM * 4);
    float* hA       = (float*)carve((size_t)NN * HDIM * 4);
    float* zcat     = (float*)carve((size_t)NGRAPH * 2 * HDIM * 4);
    float* z1       = (float*)carve((size_t)NGRAPH * 4 * HDIM * 4);
    float* z2       = (float*)carve((size_t)NGRAPH * 2 * HDIM * 4);

    _Float16* w1hi = wt;
    _Float16* w1lo = wt + 128 * 128;
    _Float16* w2hi = wt + 2 * 128 * 128;
    _Float16* w2lo = wt + 3 * 128 * 128;
    _Float16* hShi = hS;
    _Float16* hSlo = hS + (size_t)NN * HDIM;
    float*    hSf  = (float*)hS;

    const int gblk = (NN + 127) / 128;
    // contiguous zero region: edge_cnt .. cnt_g end (cursor zeroing harmless)
    size_t zero_all = (size_t)((char*)cnt_g + 2 * NGRAPH * 4 - (char*)edge_cnt);
    size_t zero_cnt = (size_t)((char*)pool_s - (char*)edge_cnt);

    if (batched) {
        const int nscan = (2 * N_NODES + 511) / 512;
        const int ablk  = (2 * N_NODES + 3) / 4;
        const int swaves = ((2 * E_EDGES + 63) >> 6) + ((2 * N_NODES + 63) >> 6);
        const int sblk = (swaves + 3) / 4;

        hipMemsetAsync(edge_cnt, 0, zero_all, stream);
        k_hist<<<1024, 256, 0, stream>>>(ei[0] + E_EDGES, ei[1] + E_EDGES,
                                         2 * E_EDGES, N_NODES, edge_cnt,
                                         W1, W2, w1hi, w1lo, w2hi, w2lo);
        k_scan_a<<<nscan, 512, 0, stream>>>(edge_cnt, row_ptr, blksum, dinv,
                                            bt[0], bt[1], 0, 2 * N_NODES, N_NODES, cnt_g);
        k_scan_b<<<1, 512, 0, stream>>>(blksum, nscan);
        k_scan_c<<<nscan, 512, 0, stream>>>(row_ptr, blksum, cursor, 2 * N_NODES, 2 * E_EDGES);
        k_fill<<<1024, 256, 0, stream>>>(ei[0], ei[1], ei[0] + E_EDGES, ei[1] + E_EDGES,
                                         2 * E_EDGES, N_NODES, 0, bt[0], bt[1],
                                         cursor, dinv, edges, gdst);

        k_gemm_split<1><<<gblk, 256, 0, stream>>>(x[0], x[1], N_NODES,
                                                  nullptr, nullptr, w1hi, w1lo, hA, 2 * N_NODES);
        k_agg<1><<<ablk, 256, 0, stream>>>(hA, dinv, row_ptr, edges, b1,
                                           hShi, hSlo, nullptr, 2 * N_NODES);
        k_gemm_split<0><<<gblk, 256, 0, stream>>>(nullptr, nullptr, 0,
                                                  hShi, hSlo, w2hi, w2lo, hA, 2 * N_NODES);
        k_agg<0><<<ablk, 256, 0, stream>>>(hA, dinv, row_ptr, edges, b2,
                                           nullptr, nullptr, hSf, 2 * N_NODES);
        k_sweep3<<<sblk, 256, 0, stream>>>(hSf, edges, gdst, dinv, bt[0], bt[1],
                                           0, 2 * N_NODES, N_NODES, 2 * E_EDGES, pool_s);
    } else {
        const int nscan = (N_NODES + 511) / 512;
        const int ablk  = (N_NODES + 3) / 4;
        const int swaves = ((E_EDGES + 63) >> 6) + ((N_NODES + 63) >> 6);
        const int sblk = (swaves + 3) / 4;

        for (int s = 0; s < 2; ++s) {
            const int* esrc = ei[s];
            const int* edst = ei[s] + E_EDGES;
            int goff = s * NGRAPH;

            // side 0: zero everything; side 1: keep pool/cnt_g accumulators
            hipMemsetAsync(edge_cnt, 0, s == 0 ? zero_all : zero_cnt, stream);
            k_hist<<<512, 256, 0, stream>>>(edst, edst, E_EDGES, 0, edge_cnt,
                                            W1, W2, w1hi, w1lo, w2hi, w2lo);
            k_scan_a<<<nscan, 512, 0, stream>>>(edge_cnt, row_ptr, blksum, dinv,
                                                bt[s], bt[s], goff, N_NODES, N_NODES, cnt_g);
            k_scan_b<<<1, 512, 0, stream>>>(blksum, nscan);
            k_scan_c<<<nscan, 512, 0, stream>>>(row_ptr, blksum, cursor, N_NODES, E_EDGES);
            k_fill<<<512, 256, 0, stream>>>(esrc, esrc, edst, edst, E_EDGES, 0, goff,
                                            bt[s], bt[s], cursor, dinv, edges, gdst);

            k_gemm_split<1><<<gblk, 256, 0, stream>>>(x[s], x[s], N_NODES,
                                                      nullptr, nullptr, w1hi, w1lo, hA, N_NODES);
            k_agg<1><<<ablk, 256, 0, stream>>>(hA, dinv, row_ptr, edges, b1,
                                               hShi, hSlo, nullptr, N_NODES);
            k_gemm_split<0><<<gblk, 256, 0, stream>>>(nullptr, nullptr, 0,
                                                      hShi, hSlo, w2hi, w2lo, hA, N_NODES);
            k_agg<0><<<ablk, 256, 0, stream>>>(hA, dinv, row_ptr, edges, b2,
                                               nullptr, nullptr, hSf, N_NODES);
            k_sweep3<<<sblk, 256, 0, stream>>>(hSf, edges, gdst, dinv, bt[s], bt[s],
                                               goff, N_NODES, N_NODES, E_EDGES, pool_s);
        }
    }

    k_gemm_pool<<<dim3(NGRAPH / 64, 2, 2), 256, 0, stream>>>(pool_s, cnt_g, W3, b3, zcat);

    k_gemm<<<dim3(NGRAPH / 64, (4 * HDIM) / 64), 256, 0, stream>>>(zcat, Wc1, bc1, z1, NGRAPH, 4 * HDIM, 2 * HDIM, 4 * HDIM, 1);
    k_gemm<<<dim3(NGRAPH / 64, (2 * HDIM) / 64), 256, 0, stream>>>(z1, Wc2, bc2, z2, NGRAPH, 2 * HDIM, 4 * HDIM, 2 * HDIM, 1);
    k_gemm<<<dim3(NGRAPH / 64, 1), 256, 0, stream>>>(z2, Wc3, bc3, out, NGRAPH, OUTC, 2 * HDIM, OUTC, 0);
}

// Round 9
// 589.188 us; speedup vs baseline: 1.8345x; 1.8345x over previous
//
#include <hip/hip_runtime.h>
#include <math.h>

#define N_NODES 50000
#define E_EDGES 500000
#define HDIM    128
#define OUTC    2
#define NGRAPH  512

typedef _Float16 f16x8 __attribute__((ext_vector_type(8)));
typedef float    f32x4 __attribute__((ext_vector_type(4)));

__device__ inline float2 unpack2(unsigned u) {
    union { unsigned v; _Float16 h[2]; } c; c.v = u;
    return make_float2((float)c.h[0], (float)c.h[1]);
}
__device__ inline unsigned pack2(float a, float b) {
    union { _Float16 h[2]; unsigned u; } c;
    c.h[0] = (_Float16)a; c.h[1] = (_Float16)b;
    return c.u;
}

// ---------------- edge histogram over dst + fused weight split-transpose ---
__global__ void k_hist(const int* __restrict__ d0, const int* __restrict__ d1,
                       int ecnt, int off1, int* __restrict__ cnt,
                       const float* __restrict__ W1, const float* __restrict__ W2,
                       _Float16* __restrict__ w1hi, _Float16* __restrict__ w1lo,
                       _Float16* __restrict__ w2hi, _Float16* __restrict__ w2lo) {
    int i = blockIdx.x * blockDim.x + threadIdx.x;
    int stride = gridDim.x * blockDim.x;
    for (int j = i; j < 128 * 128; j += stride) {
        int n = j >> 7, k = j & 127;
        float v = W1[k * 128 + n];
        _Float16 h = (_Float16)v;
        w1hi[j] = h; w1lo[j] = (_Float16)(v - (float)h);
        v = W2[k * 128 + n];
        h = (_Float16)v;
        w2hi[j] = h; w2lo[j] = (_Float16)(v - (float)h);
    }
    for (int j = i; j < ecnt; j += stride) {
        int d = (j < E_EDGES) ? d0[j] : d1[j - E_EDGES] + off1;
        atomicAdd(&cnt[d], 1);
    }
}

// ---------------- scan stage A ---------------------------------------------
__global__ void k_scan_a(const int* __restrict__ cnt, int* __restrict__ excl,
                         int* __restrict__ blksum, float* __restrict__ dinv,
                         const int* __restrict__ bt0, const int* __restrict__ bt1,
                         int goff0, int nn, int nside, float* __restrict__ cnt_g) {
    __shared__ int s[512];
    int t = threadIdx.x;
    int i = blockIdx.x * 512 + t;
    int v = 0;
    if (i < nn) {
        v = cnt[i];
        dinv[i] = 1.0f / sqrtf((float)(v + 1));
        int g = (i < nside) ? bt0[i] + goff0 : bt1[i - nside] + NGRAPH;
        atomicAdd(&cnt_g[g], 1.0f);
    }
    s[t] = v; __syncthreads();
    for (int off = 1; off < 512; off <<= 1) {
        int add = (t >= off) ? s[t - off] : 0;
        __syncthreads();
        s[t] += add;
        __syncthreads();
    }
    if (i < nn) excl[i] = s[t] - v;
    if (t == 511) blksum[blockIdx.x] = s[511];
}

// ---------------- scan stage B ---------------------------------------------
__global__ void k_scan_b(int* __restrict__ blksum, int nb) {
    __shared__ int s[512];
    int t = threadIdx.x;
    int v = (t < nb) ? blksum[t] : 0;
    s[t] = v; __syncthreads();
    for (int off = 1; off < 512; off <<= 1) {
        int add = (t >= off) ? s[t - off] : 0;
        __syncthreads();
        s[t] += add;
        __syncthreads();
    }
    if (t < nb) blksum[t] = s[t] - v;
}

// ---------------- scan stage C: finalize row_ptr AND init fill cursor ------
__global__ void k_scan_c(int* __restrict__ excl, const int* __restrict__ blksum,
                         int* __restrict__ cursor, int nn, int tot) {
    int t = threadIdx.x;
    int i = blockIdx.x * 512 + t;
    if (i < nn) {
        int v = excl[i] + blksum[blockIdx.x];
        excl[i] = v;
        cursor[i] = v;
    }
    if (i == 0) excl[nn] = tot;
}

// ---------------- CSR fill: (src, weight) + graph-of-dst, grouped by dst ---
__global__ void k_fill(const int* __restrict__ s0, const int* __restrict__ s1,
                       const int* __restrict__ d0, const int* __restrict__ d1,
                       int ecnt, int off1, int goff0,
                       const int* __restrict__ bt0, const int* __restrict__ bt1,
                       int* __restrict__ cursor,
                       const float* __restrict__ dinv, int2* __restrict__ edges,
                       int* __restrict__ gdst) {
    int i = blockIdx.x * blockDim.x + threadIdx.x;
    int stride = gridDim.x * blockDim.x;
    for (; i < ecnt; i += stride) {
        int d, sg, g;
        if (i < E_EDGES) {
            int dl = d0[i];
            sg = s0[i]; d = dl; g = bt0[dl] + goff0;
        } else {
            int dl = d1[i - E_EDGES];
            sg = s1[i - E_EDGES] + off1; d = dl + off1; g = bt1[dl] + NGRAPH;
        }
        int p = atomicAdd(&cursor[d], 1);
        float w = dinv[sg] * dinv[d];
        edges[p] = make_int2(sg, __float_as_int(w));
        gdst[p] = g;
    }
}

__device__ inline void cvt8(const float4& p, const float4& q, f16x8& h, f16x8& l) {
    float v[8] = {p.x, p.y, p.z, p.w, q.x, q.y, q.z, q.w};
#pragma unroll
    for (int i = 0; i < 8; i++) {
        _Float16 hh = (_Float16)v[i];
        h[i] = hh;
        l[i] = (_Float16)(v[i] - (float)hh);
    }
}

// ---------------- MFMA split-f16 GEMM: C(f16 plane, Mx128) = A @ W ---------
// A: ASRC=1 -> fp32 dual-base converted in-register; ASRC=0 -> split planes.
// C is written as a packed f16 plane (gather payload for the agg kernels).
template <int ASRC>
__global__ __launch_bounds__(256) void k_gemm_split(
        const float* __restrict__ A0f, const float* __restrict__ A1f, int nside,
        const _Float16* __restrict__ Ahi, const _Float16* __restrict__ Alo,
        const _Float16* __restrict__ Bhi, const _Float16* __restrict__ Blo,
        _Float16* __restrict__ C, int M) {
    __shared__ _Float16 sA[2][128][40];
    __shared__ _Float16 sB[2][128][40];
    int tid = threadIdx.x;
    int wave = tid >> 6, lane = tid & 63;
    int wm = (wave >> 1) * 64;
    int wn = (wave & 1) * 64;
    int quad = lane >> 4, fm = lane & 15;
    int row0 = blockIdx.x * 128;

    int lr = tid >> 2;
    int lk = (tid & 3) * 8;

    f32x4 acc[4][4] = {};
    const float4 z4 = make_float4(0.f, 0.f, 0.f, 0.f);

    for (int kc = 0; kc < 128; kc += 32) {
        int r1 = row0 + lr, r2 = row0 + lr + 64;
        bool ok1 = r1 < M, ok2 = r2 < M;
        f16x8 ah1, al1, ah2, al2;
        if (ASRC == 1) {
            const float* p1 = (r1 < nside) ? A0f + (size_t)r1 * 128
                                           : A1f + (size_t)(r1 - nside) * 128;
            const float* p2 = (r2 < nside) ? A0f + (size_t)r2 * 128
                                           : A1f + (size_t)(r2 - nside) * 128;
            float4 a = ok1 ? *(const float4*)(p1 + kc + lk) : z4;
            float4 b = ok1 ? *(const float4*)(p1 + kc + lk + 4) : z4;
            float4 c = ok2 ? *(const float4*)(p2 + kc + lk) : z4;
            float4 d = ok2 ? *(const float4*)(p2 + kc + lk + 4) : z4;
            cvt8(a, b, ah1, al1);
            cvt8(c, d, ah2, al2);
        } else {
            const f16x8 zf = {};
            ah1 = ok1 ? *(const f16x8*)(Ahi + (size_t)r1 * 128 + kc + lk) : zf;
            al1 = ok1 ? *(const f16x8*)(Alo + (size_t)r1 * 128 + kc + lk) : zf;
            ah2 = ok2 ? *(const f16x8*)(Ahi + (size_t)r2 * 128 + kc + lk) : zf;
            al2 = ok2 ? *(const f16x8*)(Alo + (size_t)r2 * 128 + kc + lk) : zf;
        }
        f16x8 bh1 = *(const f16x8*)(Bhi + (size_t)lr * 128 + kc + lk);
        f16x8 bl1 = *(const f16x8*)(Blo + (size_t)lr * 128 + kc + lk);
        f16x8 bh2 = *(const f16x8*)(Bhi + (size_t)(lr + 64) * 128 + kc + lk);
        f16x8 bl2 = *(const f16x8*)(Blo + (size_t)(lr + 64) * 128 + kc + lk);
        __syncthreads();
        *(f16x8*)&sA[0][lr][lk]      = ah1;
        *(f16x8*)&sA[1][lr][lk]      = al1;
        *(f16x8*)&sA[0][lr + 64][lk] = ah2;
        *(f16x8*)&sA[1][lr + 64][lk] = al2;
        *(f16x8*)&sB[0][lr][lk]      = bh1;
        *(f16x8*)&sB[1][lr][lk]      = bl1;
        *(f16x8*)&sB[0][lr + 64][lk] = bh2;
        *(f16x8*)&sB[1][lr + 64][lk] = bl2;
        __syncthreads();

        f16x8 afh[4], afl[4], bfh[4], bfl[4];
#pragma unroll
        for (int mi = 0; mi < 4; mi++) {
            afh[mi] = *(const f16x8*)&sA[0][wm + mi * 16 + fm][quad * 8];
            afl[mi] = *(const f16x8*)&sA[1][wm + mi * 16 + fm][quad * 8];
        }
#pragma unroll
        for (int ni = 0; ni < 4; ni++) {
            bfh[ni] = *(const f16x8*)&sB[0][wn + ni * 16 + fm][quad * 8];
            bfl[ni] = *(const f16x8*)&sB[1][wn + ni * 16 + fm][quad * 8];
        }
#pragma unroll
        for (int mi = 0; mi < 4; mi++)
#pragma unroll
            for (int ni = 0; ni < 4; ni++) {
                acc[mi][ni] = __builtin_amdgcn_mfma_f32_16x16x32_f16(afh[mi], bfh[ni], acc[mi][ni], 0, 0, 0);
                acc[mi][ni] = __builtin_amdgcn_mfma_f32_16x16x32_f16(afh[mi], bfl[ni], acc[mi][ni], 0, 0, 0);
                acc[mi][ni] = __builtin_amdgcn_mfma_f32_16x16x32_f16(afl[mi], bfh[ni], acc[mi][ni], 0, 0, 0);
            }
    }

#pragma unroll
    for (int mi = 0; mi < 4; mi++)
#pragma unroll
        for (int reg = 0; reg < 4; reg++) {
            int r = row0 + wm + mi * 16 + quad * 4 + reg;
            if (r >= M) continue;
#pragma unroll
            for (int ni = 0; ni < 4; ni++)
                C[(size_t)r * 128 + wn + ni * 16 + fm] = (_Float16)acc[mi][ni][reg];
        }
}

// ---------------- generic fp32 GEMM (head GEMMs) ---------------------------
__global__ __launch_bounds__(256) void k_gemm(
        const float* __restrict__ A, const float* __restrict__ B,
        const float* __restrict__ bias, float* __restrict__ C,
        int M, int Nn, int K, int ldc, int act) {
    __shared__ float As[16][64];
    __shared__ float Bs[16][68];
    int tid = threadIdx.x;
    int tx = tid & 15, ty = tid >> 4;
    int row0 = blockIdx.x * 64, col0 = blockIdx.y * 64;
    float acc[4][4] = {};
    int arow = tid >> 2;
    int acol = (tid & 3) * 4;
    int brow = tid >> 4;
    int bcol = (tid & 15) * 4;

    for (int k0 = 0; k0 < K; k0 += 16) {
        float4 av = make_float4(0.f, 0.f, 0.f, 0.f);
        int ar = row0 + arow;
        if (ar < M) av = *(const float4*)(A + (size_t)ar * K + k0 + acol);
        As[acol + 0][arow] = av.x;
        As[acol + 1][arow] = av.y;
        As[acol + 2][arow] = av.z;
        As[acol + 3][arow] = av.w;

        float4 bv = make_float4(0.f, 0.f, 0.f, 0.f);
        const float* Brow = B + (size_t)(k0 + brow) * Nn;
        int bc = col0 + bcol;
        if (bc + 3 < Nn) {
            bv = *(const float4*)(Brow + bc);
        } else {
            if (bc     < Nn) bv.x = Brow[bc];
            if (bc + 1 < Nn) bv.y = Brow[bc + 1];
            if (bc + 2 < Nn) bv.z = Brow[bc + 2];
        }
        Bs[brow][bcol + 0] = bv.x;
        Bs[brow][bcol + 1] = bv.y;
        Bs[brow][bcol + 2] = bv.z;
        Bs[brow][bcol + 3] = bv.w;
        __syncthreads();

#pragma unroll
        for (int k = 0; k < 16; k++) {
            float4 a = *(const float4*)&As[k][ty * 4];
            float4 b = *(const float4*)&Bs[k][tx * 4];
            acc[0][0] += a.x * b.x; acc[0][1] += a.x * b.y; acc[0][2] += a.x * b.z; acc[0][3] += a.x * b.w;
            acc[1][0] += a.y * b.x; acc[1][1] += a.y * b.y; acc[1][2] += a.y * b.z; acc[1][3] += a.y * b.w;
            acc[2][0] += a.z * b.x; acc[2][1] += a.z * b.y; acc[2][2] += a.z * b.z; acc[2][3] += a.z * b.w;
            acc[3][0] += a.w * b.x; acc[3][1] += a.w * b.y; acc[3][2] += a.w * b.z; acc[3][3] += a.w * b.w;
        }
        __syncthreads();
    }

#pragma unroll
    for (int i = 0; i < 4; i++) {
        int r = row0 + ty * 4 + i;
        if (r >= M) continue;
#pragma unroll
        for (int j = 0; j < 4; j++) {
            int c = col0 + tx * 4 + j;
            if (c >= Nn) continue;
            float v = acc[i][j];
            if (bias) v += bias[c];
            if (act) v = fmaxf(v, 0.0f);
            C[(size_t)r * ldc + c] = v;
        }
    }
}

// ---------------- pool GEMM: zcat[g, side*128+c] = (pool/cnt) @ W3 + b3 ----
__global__ __launch_bounds__(256) void k_gemm_pool(
        const float* __restrict__ pool, const float* __restrict__ cnt_g,
        const float* __restrict__ W, const float* __restrict__ bias,
        float* __restrict__ zcat) {
    __shared__ float As[16][64];
    __shared__ float Bs[16][68];
    int side = blockIdx.z;
    const float* A = pool + (size_t)side * NGRAPH * HDIM;
    const float* cg = cnt_g + side * NGRAPH;
    int tid = threadIdx.x;
    int tx = tid & 15, ty = tid >> 4;
    int row0 = blockIdx.x * 64, col0 = blockIdx.y * 64;
    float acc[4][4] = {};
    int arow = tid >> 2;
    int acol = (tid & 3) * 4;
    int brow = tid >> 4;
    int bcol = (tid & 15) * 4;

    for (int k0 = 0; k0 < 128; k0 += 16) {
        int ar = row0 + arow;
        float sc = 1.0f / fmaxf(cg[ar], 1.0f);
        float4 av = *(const float4*)(A + (size_t)ar * 128 + k0 + acol);
        As[acol + 0][arow] = av.x * sc;
        As[acol + 1][arow] = av.y * sc;
        As[acol + 2][arow] = av.z * sc;
        As[acol + 3][arow] = av.w * sc;

        float4 bv = *(const float4*)(W + (size_t)(k0 + brow) * 128 + col0 + bcol);
        Bs[brow][bcol + 0] = bv.x;
        Bs[brow][bcol + 1] = bv.y;
        Bs[brow][bcol + 2] = bv.z;
        Bs[brow][bcol + 3] = bv.w;
        __syncthreads();

#pragma unroll
        for (int k = 0; k < 16; k++) {
            float4 a = *(const float4*)&As[k][ty * 4];
            float4 b = *(const float4*)&Bs[k][tx * 4];
            acc[0][0] += a.x * b.x; acc[0][1] += a.x * b.y; acc[0][2] += a.x * b.z; acc[0][3] += a.x * b.w;
            acc[1][0] += a.y * b.x; acc[1][1] += a.y * b.y; acc[1][2] += a.y * b.z; acc[1][3] += a.y * b.w;
            acc[2][0] += a.z * b.x; acc[2][1] += a.z * b.y; acc[2][2] += a.z * b.z; acc[2][3] += a.z * b.w;
            acc[3][0] += a.w * b.x; acc[3][1] += a.w * b.y; acc[3][2] += a.w * b.z; acc[3][3] += a.w * b.w;
        }
        __syncthreads();
    }

#pragma unroll
    for (int i = 0; i < 4; i++) {
        int r = row0 + ty * 4 + i;
#pragma unroll
        for (int j = 0; j < 4; j++) {
            int c = col0 + tx * 4 + j;
            zcat[(size_t)r * 256 + side * 128 + c] = acc[i][j] + bias[c];
        }
    }
}

// ---------------- per-node CSR aggregation (layers 1,2) --------------------
// Round-7 structure (8 independent gathers, no arrays -> no spills), but the
// gather payload is a packed f16 row (256B vs 512B: halves gather traffic).
// PACK=1: write split hi/lo planes (GEMM A input). PACK=0: write f16 plane.
template <int PACK>
__global__ __launch_bounds__(256) void k_agg(
        const _Float16* __restrict__ H, const float* __restrict__ dinv,
        const int* __restrict__ row_ptr, const int2* __restrict__ edges,
        const float* __restrict__ bias,
        _Float16* __restrict__ outHi, _Float16* __restrict__ outLo,
        int nnodes) {
    int wave = threadIdx.x >> 6, lane = threadIdx.x & 63;
    int node = blockIdx.x * 4 + wave;
    if (node >= nnodes) return;

    float di = dinv[node];
    float2 hv = unpack2(((const unsigned*)(H + (size_t)node * HDIM))[lane]);
    float wself = di * di;
    float ax = hv.x * wself;
    float ay = hv.y * wself;

    int rs = __builtin_amdgcn_readfirstlane(row_ptr[node]);
    int re = __builtin_amdgcn_readfirstlane(row_ptr[node + 1]);

    for (int base = rs; base < re; base += 8) {
        int nrem = re - base, m = nrem - 1;
        int i1 = 1 < nrem ? 1 : m;
        int i2 = 2 < nrem ? 2 : m;
        int i3 = 3 < nrem ? 3 : m;
        int i4 = 4 < nrem ? 4 : m;
        int i5 = 5 < nrem ? 5 : m;
        int i6 = 6 < nrem ? 6 : m;
        int i7 = 7 < nrem ? 7 : m;
        int2 E0 = edges[base];
        int2 E1 = edges[base + i1];
        int2 E2 = edges[base + i2];
        int2 E3 = edges[base + i3];
        int2 E4 = edges[base + i4];
        int2 E5 = edges[base + i5];
        int2 E6 = edges[base + i6];
        int2 E7 = edges[base + i7];
        unsigned u0 = ((const unsigned*)(H + (size_t)E0.x * HDIM))[lane];
        unsigned u1 = ((const unsigned*)(H + (size_t)E1.x * HDIM))[lane];
        unsigned u2 = ((const unsigned*)(H + (size_t)E2.x * HDIM))[lane];
        unsigned u3 = ((const unsigned*)(H + (size_t)E3.x * HDIM))[lane];
        unsigned u4 = ((const unsigned*)(H + (size_t)E4.x * HDIM))[lane];
        unsigned u5 = ((const unsigned*)(H + (size_t)E5.x * HDIM))[lane];
        unsigned u6 = ((const unsigned*)(H + (size_t)E6.x * HDIM))[lane];
        unsigned u7 = ((const unsigned*)(H + (size_t)E7.x * HDIM))[lane];
        float w0 = __int_as_float(E0.y);
        float w1 = 1 < nrem ? __int_as_float(E1.y) : 0.f;
        float w2 = 2 < nrem ? __int_as_float(E2.y) : 0.f;
        float w3 = 3 < nrem ? __int_as_float(E3.y) : 0.f;
        float w4 = 4 < nrem ? __int_as_float(E4.y) : 0.f;
        float w5 = 5 < nrem ? __int_as_float(E5.y) : 0.f;
        float w6 = 6 < nrem ? __int_as_float(E6.y) : 0.f;
        float w7 = 7 < nrem ? __int_as_float(E7.y) : 0.f;
        float2 v0 = unpack2(u0), v1 = unpack2(u1), v2 = unpack2(u2), v3 = unpack2(u3);
        float2 v4 = unpack2(u4), v5 = unpack2(u5), v6 = unpack2(u6), v7 = unpack2(u7);
        ax = fmaf(v0.x, w0, ax); ay = fmaf(v0.y, w0, ay);
        ax = fmaf(v1.x, w1, ax); ay = fmaf(v1.y, w1, ay);
        ax = fmaf(v2.x, w2, ax); ay = fmaf(v2.y, w2, ay);
        ax = fmaf(v3.x, w3, ax); ay = fmaf(v3.y, w3, ay);
        ax = fmaf(v4.x, w4, ax); ay = fmaf(v4.y, w4, ay);
        ax = fmaf(v5.x, w5, ax); ay = fmaf(v5.y, w5, ay);
        ax = fmaf(v6.x, w6, ax); ay = fmaf(v6.y, w6, ay);
        ax = fmaf(v7.x, w7, ax); ay = fmaf(v7.y, w7, ay);
    }

    float ox = fmaxf(ax + bias[lane * 2],     0.0f);
    float oy = fmaxf(ay + bias[lane * 2 + 1], 0.0f);
    if (PACK) {
        _Float16 hx = (_Float16)ox, hy = (_Float16)oy;
        _Float16 lx = (_Float16)(ox - (float)hx), ly = (_Float16)(oy - (float)hy);
        union { _Float16 h[2]; unsigned u; } ph, pl;
        ph.h[0] = hx; ph.h[1] = hy;
        pl.h[0] = lx; pl.h[1] = ly;
        ((unsigned*)(outHi + (size_t)node * HDIM))[lane] = ph.u;
        ((unsigned*)(outLo + (size_t)node * HDIM))[lane] = pl.u;
    } else {
        ((unsigned*)(outHi + (size_t)node * HDIM))[lane] = pack2(ox, oy);
    }
}

// ---------------- layer-3 pooled aggregation: linear edge sweep ------------
// Single-graph 64-edge chunks (gdst[e0]==gdst[e1-1], ~94%) take the branch-
// free 8-gather path with ONE flush; boundary chunks walk per-edge.
__global__ __launch_bounds__(256) void k_sweep3(
        const _Float16* __restrict__ H, const int2* __restrict__ edges,
        const int* __restrict__ gdst, const float* __restrict__ dinv,
        const int* __restrict__ bt0, const int* __restrict__ bt1,
        int goff0, int nnodes, int nside, int nedges,
        float* __restrict__ pool) {
    int lane = threadIdx.x & 63;
    int wid = blockIdx.x * 4 + (threadIdx.x >> 6);
    int ewaves = (nedges + 63) >> 6;

    if (wid < ewaves) {
        int e0 = wid << 6;
        int e1 = e0 + 64; if (e1 > nedges) e1 = nedges;
        int gfirst = __builtin_amdgcn_readfirstlane(gdst[e0]);
        int glast  = __builtin_amdgcn_readfirstlane(gdst[e1 - 1]);
        float ax = 0.f, ay = 0.f;

        if (gfirst == glast) {
            for (int base = e0; base < e1; base += 8) {
                int nrem = e1 - base, m = nrem - 1;
                int i1 = 1 < nrem ? 1 : m;
                int i2 = 2 < nrem ? 2 : m;
                int i3 = 3 < nrem ? 3 : m;
                int i4 = 4 < nrem ? 4 : m;
                int i5 = 5 < nrem ? 5 : m;
                int i6 = 6 < nrem ? 6 : m;
                int i7 = 7 < nrem ? 7 : m;
                int2 E0 = edges[base];
                int2 E1 = edges[base + i1];
                int2 E2 = edges[base + i2];
                int2 E3 = edges[base + i3];
                int2 E4 = edges[base + i4];
                int2 E5 = edges[base + i5];
                int2 E6 = edges[base + i6];
                int2 E7 = edges[base + i7];
                unsigned u0 = ((const unsigned*)(H + (size_t)E0.x * HDIM))[lane];
                unsigned u1 = ((const unsigned*)(H + (size_t)E1.x * HDIM))[lane];
                unsigned u2 = ((const unsigned*)(H + (size_t)E2.x * HDIM))[lane];
                unsigned u3 = ((const unsigned*)(H + (size_t)E3.x * HDIM))[lane];
                unsigned u4 = ((const unsigned*)(H + (size_t)E4.x * HDIM))[lane];
                unsigned u5 = ((const unsigned*)(H + (size_t)E5.x * HDIM))[lane];
                unsigned u6 = ((const unsigned*)(H + (size_t)E6.x * HDIM))[lane];
                unsigned u7 = ((const unsigned*)(H + (size_t)E7.x * HDIM))[lane];
                float w0 = __int_as_float(E0.y);
                float w1 = 1 < nrem ? __int_as_float(E1.y) : 0.f;
                float w2 = 2 < nrem ? __int_as_float(E2.y) : 0.f;
                float w3 = 3 < nrem ? __int_as_float(E3.y) : 0.f;
                float w4 = 4 < nrem ? __int_as_float(E4.y) : 0.f;
                float w5 = 5 < nrem ? __int_as_float(E5.y) : 0.f;
                float w6 = 6 < nrem ? __int_as_float(E6.y) : 0.f;
                float w7 = 7 < nrem ? __int_as_float(E7.y) : 0.f;
                float2 v0 = unpack2(u0), v1 = unpack2(u1), v2 = unpack2(u2), v3 = unpack2(u3);
                float2 v4 = unpack2(u4), v5 = unpack2(u5), v6 = unpack2(u6), v7 = unpack2(u7);
                ax = fmaf(v0.x, w0, ax); ay = fmaf(v0.y, w0, ay);
                ax = fmaf(v1.x, w1, ax); ay = fmaf(v1.y, w1, ay);
                ax = fmaf(v2.x, w2, ax); ay = fmaf(v2.y, w2, ay);
                ax = fmaf(v3.x, w3, ax); ay = fmaf(v3.y, w3, ay);
                ax = fmaf(v4.x, w4, ax); ay = fmaf(v4.y, w4, ay);
                ax = fmaf(v5.x, w5, ax); ay = fmaf(v5.y, w5, ay);
                ax = fmaf(v6.x, w6, ax); ay = fmaf(v6.y, w6, ay);
                ax = fmaf(v7.x, w7, ax); ay = fmaf(v7.y, w7, ay);
            }
            float* p = pool + (size_t)gfirst * HDIM + lane * 2;
            atomicAdd(p, ax); atomicAdd(p + 1, ay);
        } else {
            int gcur = gfirst;
            for (int e = e0; e < e1; e++) {
                int2 E = edges[e];
                int g = __builtin_amdgcn_readfirstlane(gdst[e]);
                if (g != gcur) {
                    float* p = pool + (size_t)gcur * HDIM + lane * 2;
                    atomicAdd(p, ax); atomicAdd(p + 1, ay);
                    ax = 0.f; ay = 0.f;
                    gcur = g;
                }
                float w = __int_as_float(E.y);
                float2 v = unpack2(((const unsigned*)(H + (size_t)E.x * HDIM))[lane]);
                ax = fmaf(v.x, w, ax);
                ay = fmaf(v.y, w, ay);
            }
            float* p = pool + (size_t)gcur * HDIM + lane * 2;
            atomicAdd(p, ax); atomicAdd(p + 1, ay);
        }
    } else {
        // self-loop streaming sweep
        int wid2 = wid - ewaves;
        int n0 = wid2 << 6;
        if (n0 >= nnodes) return;
        int n1 = n0 + 64; if (n1 > nnodes) n1 = nnodes;
        float ax = 0.f, ay = 0.f;
        int gcur = (n0 < nside) ? bt0[n0] + goff0 : bt1[n0 - nside] + NGRAPH;
        gcur = __builtin_amdgcn_readfirstlane(gcur);
        for (int n = n0; n < n1; n++) {
            int g = (n < nside) ? bt0[n] + goff0 : bt1[n - nside] + NGRAPH;
            g = __builtin_amdgcn_readfirstlane(g);
            float dn = dinv[n];
            float w = dn * dn;
            float2 v = unpack2(((const unsigned*)(H + (size_t)n * HDIM))[lane]);
            if (g != gcur) {
                float* p = pool + (size_t)gcur * HDIM + lane * 2;
                atomicAdd(p, ax); atomicAdd(p + 1, ay);
                ax = 0.f; ay = 0.f;
                gcur = g;
            }
            ax = fmaf(v.x, w, ax);
            ay = fmaf(v.y, w, ay);
        }
        float* p = pool + (size_t)gcur * HDIM + lane * 2;
        atomicAdd(p, ax); atomicAdd(p + 1, ay);
    }
}

extern "C" void kernel_launch(void* const* d_in, const int* in_sizes, int n_in,
                              void* d_out, int out_size, void* d_ws, size_t ws_size,
                              hipStream_t stream) {
    (void)in_sizes; (void)n_in; (void)out_size;

    const float* x[2]  = {(const float*)d_in[0], (const float*)d_in[1]};
    const int*   ei[2] = {(const int*)d_in[2], (const int*)d_in[3]};
    const int*   bt[2] = {(const int*)d_in[4], (const int*)d_in[5]};
    const float* W1  = (const float*)d_in[6];  const float* b1  = (const float*)d_in[7];
    const float* W2  = (const float*)d_in[8];  const float* b2  = (const float*)d_in[9];
    const float* W3  = (const float*)d_in[10]; const float* b3  = (const float*)d_in[11];
    const float* Wc1 = (const float*)d_in[12]; const float* bc1 = (const float*)d_in[13];
    const float* Wc2 = (const float*)d_in[14]; const float* bc2 = (const float*)d_in[15];
    const float* Wc3 = (const float*)d_in[16]; const float* bc3 = (const float*)d_in[17];
    float* out = (float*)d_out;

    const bool batched = ws_size >= 120ull * 1000 * 1000;
    const int NN = batched ? 2 * N_NODES : N_NODES;
    const int NE = batched ? 2 * E_EDGES : E_EDGES;

    char* ws = (char*)d_ws;
    size_t off = 0;
    auto carve = [&](size_t bytes) -> char* {
        char* p = ws + off;
        off += (bytes + 255) & ~(size_t)255;
        return p;
    };

    int*   edge_cnt = (int*)  carve((size_t)NN * 4);
    int*   cursor   = (int*)  carve((size_t)NN * 4);
    float* pool_s   = (float*)carve((size_t)2 * NGRAPH * HDIM * 4);
    float* cnt_g    = (float*)carve((size_t)2 * NGRAPH * 4);
    float* dinv     = (float*)carve((size_t)NN * 4);
    int*   row_ptr  = (int*)  carve((size_t)(NN + 1) * 4);
    int2*  edges    = (int2*) carve((size_t)NE * 8);
    int*   gdst     = (int*)  carve((size_t)NE * 4);
    int*   blksum   = (int*)  carve(1024 * 4);
    _Float16* wt    = (_Float16*)carve(4 * 128 * 128 * 2);
    _Float16* hS    = (_Float16*)carve((size_t)NN * HDIM * 4);  // hi+lo planes
    _Float16* hA    = (_Float16*)carve((size_t)NN * HDIM * 2);  // f16 gather plane
    float* zcat     = (float*)carve((size_t)NGRAPH * 2 * HDIM * 4);
    float* z1       = (float*)carve((size_t)NGRAPH * 4 * HDIM * 4);
    float* z2       = (float*)carve((size_t)NGRAPH * 2 * HDIM * 4);

    _Float16* w1hi = wt;
    _Float16* w1lo = wt + 128 * 128;
    _Float16* w2hi = wt + 2 * 128 * 128;
    _Float16* w2lo = wt + 3 * 128 * 128;
    _Float16* hShi = hS;                                // also reused as h2 f16 plane
    _Float16* hSlo = hS + (size_t)NN * HDIM;

    const int gblk = (NN + 127) / 128;
    size_t zero_all = (size_t)((char*)cnt_g + 2 * NGRAPH * 4 - (char*)edge_cnt);
    size_t zero_cnt = (size_t)((char*)pool_s - (char*)edge_cnt);

    if (batched) {
        const int nscan = (2 * N_NODES + 511) / 512;
        const int ablk  = (2 * N_NODES + 3) / 4;
        const int swaves = ((2 * E_EDGES + 63) >> 6) + ((2 * N_NODES + 63) >> 6);
        const int sblk = (swaves + 3) / 4;

        hipMemsetAsync(edge_cnt, 0, zero_all, stream);
        k_hist<<<1024, 256, 0, stream>>>(ei[0] + E_EDGES, ei[1] + E_EDGES,
                                         2 * E_EDGES, N_NODES, edge_cnt,
                                         W1, W2, w1hi, w1lo, w2hi, w2lo);
        k_scan_a<<<nscan, 512, 0, stream>>>(edge_cnt, row_ptr, blksum, dinv,
                                            bt[0], bt[1], 0, 2 * N_NODES, N_NODES, cnt_g);
        k_scan_b<<<1, 512, 0, stream>>>(blksum, nscan);
        k_scan_c<<<nscan, 512, 0, stream>>>(row_ptr, blksum, cursor, 2 * N_NODES, 2 * E_EDGES);
        k_fill<<<1024, 256, 0, stream>>>(ei[0], ei[1], ei[0] + E_EDGES, ei[1] + E_EDGES,
                                         2 * E_EDGES, N_NODES, 0, bt[0], bt[1],
                                         cursor, dinv, edges, gdst);

        k_gemm_split<1><<<gblk, 256, 0, stream>>>(x[0], x[1], N_NODES,
                                                  nullptr, nullptr, w1hi, w1lo, hA, 2 * N_NODES);
        k_agg<1><<<ablk, 256, 0, stream>>>(hA, dinv, row_ptr, edges, b1,
                                           hShi, hSlo, 2 * N_NODES);
        k_gemm_split<0><<<gblk, 256, 0, stream>>>(nullptr, nullptr, 0,
                                                  hShi, hSlo, w2hi, w2lo, hA, 2 * N_NODES);
        k_agg<0><<<ablk, 256, 0, stream>>>(hA, dinv, row_ptr, edges, b2,
                                           hShi, nullptr, 2 * N_NODES);
        k_sweep3<<<sblk, 256, 0, stream>>>(hShi, edges, gdst, dinv, bt[0], bt[1],
                                           0, 2 * N_NODES, N_NODES, 2 * E_EDGES, pool_s);
    } else {
        const int nscan = (N_NODES + 511) / 512;
        const int ablk  = (N_NODES + 3) / 4;
        const int swaves = ((E_EDGES + 63) >> 6) + ((N_NODES + 63) >> 6);
        const int sblk = (swaves + 3) / 4;

        for (int s = 0; s < 2; ++s) {
            const int* esrc = ei[s];
            const int* edst = ei[s] + E_EDGES;
            int goff = s * NGRAPH;

            hipMemsetAsync(edge_cnt, 0, s == 0 ? zero_all : zero_cnt, stream);
            k_hist<<<512, 256, 0, stream>>>(edst, edst, E_EDGES, 0, edge_cnt,
                                            W1, W2, w1hi, w1lo, w2hi, w2lo);
            k_scan_a<<<nscan, 512, 0, stream>>>(edge_cnt, row_ptr, blksum, dinv,
                                                bt[s], bt[s], goff, N_NODES, N_NODES, cnt_g);
            k_scan_b<<<1, 512, 0, stream>>>(blksum, nscan);
            k_scan_c<<<nscan, 512, 0, stream>>>(row_ptr, blksum, cursor, N_NODES, E_EDGES);
            k_fill<<<512, 256, 0, stream>>>(esrc, esrc, edst, edst, E_EDGES, 0, goff,
                                            bt[s], bt[s], cursor, dinv, edges, gdst);

            k_gemm_split<1><<<gblk, 256, 0, stream>>>(x[s], x[s], N_NODES,
                                                      nullptr, nullptr, w1hi, w1lo, hA, N_NODES);
            k_agg<1><<<ablk, 256, 0, stream>>>(hA, dinv, row_ptr, edges, b1,
                                               hShi, hSlo, N_NODES);
            k_gemm_split<0><<<gblk, 256, 0, stream>>>(nullptr, nullptr, 0,
                                                      hShi, hSlo, w2hi, w2lo, hA, N_NODES);
            k_agg<0><<<ablk, 256, 0, stream>>>(hA, dinv, row_ptr, edges, b2,
                                               hShi, nullptr, N_NODES);
            k_sweep3<<<sblk, 256, 0, stream>>>(hShi, edges, gdst, dinv, bt[s], bt[s],
                                               goff, N_NODES, N_NODES, E_EDGES, pool_s);
        }
    }

    k_gemm_pool<<<dim3(NGRAPH / 64, 2, 2), 256, 0, stream>>>(pool_s, cnt_g, W3, b3, zcat);

    k_gemm<<<dim3(NGRAPH / 64, (4 * HDIM) / 64), 256, 0, stream>>>(zcat, Wc1, bc1, z1, NGRAPH, 4 * HDIM, 2 * HDIM, 4 * HDIM, 1);
    k_gemm<<<dim3(NGRAPH / 64, (2 * HDIM) / 64), 256, 0, stream>>>(z1, Wc2, bc2, z2, NGRAPH, 2 * HDIM, 4 * HDIM, 2 * HDIM, 1);
    k_gemm<<<dim3(NGRAPH / 64, 1), 256, 0, stream>>>(z2, Wc3, bc3, out, NGRAPH, OUTC, 2 * HDIM, OUTC, 0);
}

// Round 10
// 579.357 us; speedup vs baseline: 1.8657x; 1.0170x over previous
//
#include <hip/hip_runtime.h>
#include <math.h>

#define N_NODES 50000
#define E_EDGES 500000
#define HDIM    128
#define OUTC    2
#define NGRAPH  512

typedef _Float16 f16x8 __attribute__((ext_vector_type(8)));
typedef float    f32x4 __attribute__((ext_vector_type(4)));

__device__ inline float2 unpack2(unsigned u) {
    union { unsigned v; _Float16 h[2]; } c; c.v = u;
    return make_float2((float)c.h[0], (float)c.h[1]);
}
__device__ inline unsigned pack2(float a, float b) {
    union { _Float16 h[2]; unsigned u; } c;
    c.h[0] = (_Float16)a; c.h[1] = (_Float16)b;
    return c.u;
}

// ---------------- edge histogram over dst + fused weight split-transpose ---
__global__ void k_hist(const int* __restrict__ d0, const int* __restrict__ d1,
                       int ecnt, int off1, int* __restrict__ cnt,
                       const float* __restrict__ W1, const float* __restrict__ W2,
                       _Float16* __restrict__ w1hi, _Float16* __restrict__ w1lo,
                       _Float16* __restrict__ w2hi, _Float16* __restrict__ w2lo) {
    int i = blockIdx.x * blockDim.x + threadIdx.x;
    int stride = gridDim.x * blockDim.x;
    for (int j = i; j < 128 * 128; j += stride) {
        int n = j >> 7, k = j & 127;
        float v = W1[k * 128 + n];
        _Float16 h = (_Float16)v;
        w1hi[j] = h; w1lo[j] = (_Float16)(v - (float)h);
        v = W2[k * 128 + n];
        h = (_Float16)v;
        w2hi[j] = h; w2lo[j] = (_Float16)(v - (float)h);
    }
    for (int j = i; j < ecnt; j += stride) {
        int d = (j < E_EDGES) ? d0[j] : d1[j - E_EDGES] + off1;
        atomicAdd(&cnt[d], 1);
    }
}

// ---------------- scan stage A ---------------------------------------------
__global__ void k_scan_a(const int* __restrict__ cnt, int* __restrict__ excl,
                         int* __restrict__ blksum, float* __restrict__ dinv,
                         const int* __restrict__ bt0, const int* __restrict__ bt1,
                         int goff0, int nn, int nside, float* __restrict__ cnt_g) {
    __shared__ int s[512];
    int t = threadIdx.x;
    int i = blockIdx.x * 512 + t;
    int v = 0;
    if (i < nn) {
        v = cnt[i];
        dinv[i] = 1.0f / sqrtf((float)(v + 1));
        int g = (i < nside) ? bt0[i] + goff0 : bt1[i - nside] + NGRAPH;
        atomicAdd(&cnt_g[g], 1.0f);
    }
    s[t] = v; __syncthreads();
    for (int off = 1; off < 512; off <<= 1) {
        int add = (t >= off) ? s[t - off] : 0;
        __syncthreads();
        s[t] += add;
        __syncthreads();
    }
    if (i < nn) excl[i] = s[t] - v;
    if (t == 511) blksum[blockIdx.x] = s[511];
}

// ---------------- scan stage B ---------------------------------------------
__global__ void k_scan_b(int* __restrict__ blksum, int nb) {
    __shared__ int s[512];
    int t = threadIdx.x;
    int v = (t < nb) ? blksum[t] : 0;
    s[t] = v; __syncthreads();
    for (int off = 1; off < 512; off <<= 1) {
        int add = (t >= off) ? s[t - off] : 0;
        __syncthreads();
        s[t] += add;
        __syncthreads();
    }
    if (t < nb) blksum[t] = s[t] - v;
}

// ---------------- scan stage C: finalize row_ptr AND init fill cursor ------
__global__ void k_scan_c(int* __restrict__ excl, const int* __restrict__ blksum,
                         int* __restrict__ cursor, int nn, int tot) {
    int t = threadIdx.x;
    int i = blockIdx.x * 512 + t;
    if (i < nn) {
        int v = excl[i] + blksum[blockIdx.x];
        excl[i] = v;
        cursor[i] = v;
    }
    if (i == 0) excl[nn] = tot;
}

// ---------------- CSR fill: int4 record (src, w, gdst, 0) grouped by dst ---
__global__ void k_fill(const int* __restrict__ s0, const int* __restrict__ s1,
                       const int* __restrict__ d0, const int* __restrict__ d1,
                       int ecnt, int off1, int goff0,
                       const int* __restrict__ bt0, const int* __restrict__ bt1,
                       int* __restrict__ cursor,
                       const float* __restrict__ dinv, int4* __restrict__ edges) {
    int i = blockIdx.x * blockDim.x + threadIdx.x;
    int stride = gridDim.x * blockDim.x;
    for (; i < ecnt; i += stride) {
        int d, sg, g;
        if (i < E_EDGES) {
            int dl = d0[i];
            sg = s0[i]; d = dl; g = bt0[dl] + goff0;
        } else {
            int dl = d1[i - E_EDGES];
            sg = s1[i - E_EDGES] + off1; d = dl + off1; g = bt1[dl] + NGRAPH;
        }
        int p = atomicAdd(&cursor[d], 1);
        float w = dinv[sg] * dinv[d];
        edges[p] = make_int4(sg, __float_as_int(w), g, 0);
    }
}

__device__ inline void cvt8(const float4& p, const float4& q, f16x8& h, f16x8& l) {
    float v[8] = {p.x, p.y, p.z, p.w, q.x, q.y, q.z, q.w};
#pragma unroll
    for (int i = 0; i < 8; i++) {
        _Float16 hh = (_Float16)v[i];
        h[i] = hh;
        l[i] = (_Float16)(v[i] - (float)hh);
    }
}

// ---------------- MFMA split-f16 GEMM: C(f16 plane, Mx128) = A @ W ---------
template <int ASRC>
__global__ __launch_bounds__(256) void k_gemm_split(
        const float* __restrict__ A0f, const float* __restrict__ A1f, int nside,
        const _Float16* __restrict__ Ahi, const _Float16* __restrict__ Alo,
        const _Float16* __restrict__ Bhi, const _Float16* __restrict__ Blo,
        _Float16* __restrict__ C, int M) {
    __shared__ _Float16 sA[2][128][40];
    __shared__ _Float16 sB[2][128][40];
    int tid = threadIdx.x;
    int wave = tid >> 6, lane = tid & 63;
    int wm = (wave >> 1) * 64;
    int wn = (wave & 1) * 64;
    int quad = lane >> 4, fm = lane & 15;
    int row0 = blockIdx.x * 128;

    int lr = tid >> 2;
    int lk = (tid & 3) * 8;

    f32x4 acc[4][4] = {};
    const float4 z4 = make_float4(0.f, 0.f, 0.f, 0.f);

    for (int kc = 0; kc < 128; kc += 32) {
        int r1 = row0 + lr, r2 = row0 + lr + 64;
        bool ok1 = r1 < M, ok2 = r2 < M;
        f16x8 ah1, al1, ah2, al2;
        if (ASRC == 1) {
            const float* p1 = (r1 < nside) ? A0f + (size_t)r1 * 128
                                           : A1f + (size_t)(r1 - nside) * 128;
            const float* p2 = (r2 < nside) ? A0f + (size_t)r2 * 128
                                           : A1f + (size_t)(r2 - nside) * 128;
            float4 a = ok1 ? *(const float4*)(p1 + kc + lk) : z4;
            float4 b = ok1 ? *(const float4*)(p1 + kc + lk + 4) : z4;
            float4 c = ok2 ? *(const float4*)(p2 + kc + lk) : z4;
            float4 d = ok2 ? *(const float4*)(p2 + kc + lk + 4) : z4;
            cvt8(a, b, ah1, al1);
            cvt8(c, d, ah2, al2);
        } else {
            const f16x8 zf = {};
            ah1 = ok1 ? *(const f16x8*)(Ahi + (size_t)r1 * 128 + kc + lk) : zf;
            al1 = ok1 ? *(const f16x8*)(Alo + (size_t)r1 * 128 + kc + lk) : zf;
            ah2 = ok2 ? *(const f16x8*)(Ahi + (size_t)r2 * 128 + kc + lk) : zf;
            al2 = ok2 ? *(const f16x8*)(Alo + (size_t)r2 * 128 + kc + lk) : zf;
        }
        f16x8 bh1 = *(const f16x8*)(Bhi + (size_t)lr * 128 + kc + lk);
        f16x8 bl1 = *(const f16x8*)(Blo + (size_t)lr * 128 + kc + lk);
        f16x8 bh2 = *(const f16x8*)(Bhi + (size_t)(lr + 64) * 128 + kc + lk);
        f16x8 bl2 = *(const f16x8*)(Blo + (size_t)(lr + 64) * 128 + kc + lk);
        __syncthreads();
        *(f16x8*)&sA[0][lr][lk]      = ah1;
        *(f16x8*)&sA[1][lr][lk]      = al1;
        *(f16x8*)&sA[0][lr + 64][lk] = ah2;
        *(f16x8*)&sA[1][lr + 64][lk] = al2;
        *(f16x8*)&sB[0][lr][lk]      = bh1;
        *(f16x8*)&sB[1][lr][lk]      = bl1;
        *(f16x8*)&sB[0][lr + 64][lk] = bh2;
        *(f16x8*)&sB[1][lr + 64][lk] = bl2;
        __syncthreads();

        f16x8 afh[4], afl[4], bfh[4], bfl[4];
#pragma unroll
        for (int mi = 0; mi < 4; mi++) {
            afh[mi] = *(const f16x8*)&sA[0][wm + mi * 16 + fm][quad * 8];
            afl[mi] = *(const f16x8*)&sA[1][wm + mi * 16 + fm][quad * 8];
        }
#pragma unroll
        for (int ni = 0; ni < 4; ni++) {
            bfh[ni] = *(const f16x8*)&sB[0][wn + ni * 16 + fm][quad * 8];
            bfl[ni] = *(const f16x8*)&sB[1][wn + ni * 16 + fm][quad * 8];
        }
#pragma unroll
        for (int mi = 0; mi < 4; mi++)
#pragma unroll
            for (int ni = 0; ni < 4; ni++) {
                acc[mi][ni] = __builtin_amdgcn_mfma_f32_16x16x32_f16(afh[mi], bfh[ni], acc[mi][ni], 0, 0, 0);
                acc[mi][ni] = __builtin_amdgcn_mfma_f32_16x16x32_f16(afh[mi], bfl[ni], acc[mi][ni], 0, 0, 0);
                acc[mi][ni] = __builtin_amdgcn_mfma_f32_16x16x32_f16(afl[mi], bfh[ni], acc[mi][ni], 0, 0, 0);
            }
    }

#pragma unroll
    for (int mi = 0; mi < 4; mi++)
#pragma unroll
        for (int reg = 0; reg < 4; reg++) {
            int r = row0 + wm + mi * 16 + quad * 4 + reg;
            if (r >= M) continue;
#pragma unroll
            for (int ni = 0; ni < 4; ni++)
                C[(size_t)r * 128 + wn + ni * 16 + fm] = (_Float16)acc[mi][ni][reg];
        }
}

// ---------------- generic fp32 GEMM (head GEMMs) ---------------------------
__global__ __launch_bounds__(256) void k_gemm(
        const float* __restrict__ A, const float* __restrict__ B,
        const float* __restrict__ bias, float* __restrict__ C,
        int M, int Nn, int K, int ldc, int act) {
    __shared__ float As[16][64];
    __shared__ float Bs[16][68];
    int tid = threadIdx.x;
    int tx = tid & 15, ty = tid >> 4;
    int row0 = blockIdx.x * 64, col0 = blockIdx.y * 64;
    float acc[4][4] = {};
    int arow = tid >> 2;
    int acol = (tid & 3) * 4;
    int brow = tid >> 4;
    int bcol = (tid & 15) * 4;

    for (int k0 = 0; k0 < K; k0 += 16) {
        float4 av = make_float4(0.f, 0.f, 0.f, 0.f);
        int ar = row0 + arow;
        if (ar < M) av = *(const float4*)(A + (size_t)ar * K + k0 + acol);
        As[acol + 0][arow] = av.x;
        As[acol + 1][arow] = av.y;
        As[acol + 2][arow] = av.z;
        As[acol + 3][arow] = av.w;

        float4 bv = make_float4(0.f, 0.f, 0.f, 0.f);
        const float* Brow = B + (size_t)(k0 + brow) * Nn;
        int bc = col0 + bcol;
        if (bc + 3 < Nn) {
            bv = *(const float4*)(Brow + bc);
        } else {
            if (bc     < Nn) bv.x = Brow[bc];
            if (bc + 1 < Nn) bv.y = Brow[bc + 1];
            if (bc + 2 < Nn) bv.z = Brow[bc + 2];
        }
        Bs[brow][bcol + 0] = bv.x;
        Bs[brow][bcol + 1] = bv.y;
        Bs[brow][bcol + 2] = bv.z;
        Bs[brow][bcol + 3] = bv.w;
        __syncthreads();

#pragma unroll
        for (int k = 0; k < 16; k++) {
            float4 a = *(const float4*)&As[k][ty * 4];
            float4 b = *(const float4*)&Bs[k][tx * 4];
            acc[0][0] += a.x * b.x; acc[0][1] += a.x * b.y; acc[0][2] += a.x * b.z; acc[0][3] += a.x * b.w;
            acc[1][0] += a.y * b.x; acc[1][1] += a.y * b.y; acc[1][2] += a.y * b.z; acc[1][3] += a.y * b.w;
            acc[2][0] += a.z * b.x; acc[2][1] += a.z * b.y; acc[2][2] += a.z * b.z; acc[2][3] += a.z * b.w;
            acc[3][0] += a.w * b.x; acc[3][1] += a.w * b.y; acc[3][2] += a.w * b.z; acc[3][3] += a.w * b.w;
        }
        __syncthreads();
    }

#pragma unroll
    for (int i = 0; i < 4; i++) {
        int r = row0 + ty * 4 + i;
        if (r >= M) continue;
#pragma unroll
        for (int j = 0; j < 4; j++) {
            int c = col0 + tx * 4 + j;
            if (c >= Nn) continue;
            float v = acc[i][j];
            if (bias) v += bias[c];
            if (act) v = fmaxf(v, 0.0f);
            C[(size_t)r * ldc + c] = v;
        }
    }
}

// ---------------- pool GEMM: zcat[g, side*128+c] = (pool/cnt) @ W3 + b3 ----
__global__ __launch_bounds__(256) void k_gemm_pool(
        const float* __restrict__ pool, const float* __restrict__ cnt_g,
        const float* __restrict__ W, const float* __restrict__ bias,
        float* __restrict__ zcat) {
    __shared__ float As[16][64];
    __shared__ float Bs[16][68];
    int side = blockIdx.z;
    const float* A = pool + (size_t)side * NGRAPH * HDIM;
    const float* cg = cnt_g + side * NGRAPH;
    int tid = threadIdx.x;
    int tx = tid & 15, ty = tid >> 4;
    int row0 = blockIdx.x * 64, col0 = blockIdx.y * 64;
    float acc[4][4] = {};
    int arow = tid >> 2;
    int acol = (tid & 3) * 4;
    int brow = tid >> 4;
    int bcol = (tid & 15) * 4;

    for (int k0 = 0; k0 < 128; k0 += 16) {
        int ar = row0 + arow;
        float sc = 1.0f / fmaxf(cg[ar], 1.0f);
        float4 av = *(const float4*)(A + (size_t)ar * 128 + k0 + acol);
        As[acol + 0][arow] = av.x * sc;
        As[acol + 1][arow] = av.y * sc;
        As[acol + 2][arow] = av.z * sc;
        As[acol + 3][arow] = av.w * sc;

        float4 bv = *(const float4*)(W + (size_t)(k0 + brow) * 128 + col0 + bcol);
        Bs[brow][bcol + 0] = bv.x;
        Bs[brow][bcol + 1] = bv.y;
        Bs[brow][bcol + 2] = bv.z;
        Bs[brow][bcol + 3] = bv.w;
        __syncthreads();

#pragma unroll
        for (int k = 0; k < 16; k++) {
            float4 a = *(const float4*)&As[k][ty * 4];
            float4 b = *(const float4*)&Bs[k][tx * 4];
            acc[0][0] += a.x * b.x; acc[0][1] += a.x * b.y; acc[0][2] += a.x * b.z; acc[0][3] += a.x * b.w;
            acc[1][0] += a.y * b.x; acc[1][1] += a.y * b.y; acc[1][2] += a.y * b.z; acc[1][3] += a.y * b.w;
            acc[2][0] += a.z * b.x; acc[2][1] += a.z * b.y; acc[2][2] += a.z * b.z; acc[2][3] += a.z * b.w;
            acc[3][0] += a.w * b.x; acc[3][1] += a.w * b.y; acc[3][2] += a.w * b.z; acc[3][3] += a.w * b.w;
        }
        __syncthreads();
    }

#pragma unroll
    for (int i = 0; i < 4; i++) {
        int r = row0 + ty * 4 + i;
#pragma unroll
        for (int j = 0; j < 4; j++) {
            int c = col0 + tx * 4 + j;
            zcat[(size_t)r * 256 + side * 128 + c] = acc[i][j] + bias[c];
        }
    }
}

// ---------------- per-node CSR aggregation (layers 1,2) --------------------
// f16 gather payload. Full 8-groups are clamp-free; single clamped tail.
template <int PACK>
__global__ __launch_bounds__(256) void k_agg(
        const _Float16* __restrict__ H, const float* __restrict__ dinv,
        const int* __restrict__ row_ptr, const int4* __restrict__ edges,
        const float* __restrict__ bias,
        _Float16* __restrict__ outHi, _Float16* __restrict__ outLo,
        int nnodes) {
    int wave = threadIdx.x >> 6, lane = threadIdx.x & 63;
    int node = blockIdx.x * 4 + wave;
    if (node >= nnodes) return;

    float di = dinv[node];
    float2 hv = unpack2(((const unsigned*)(H + (size_t)node * HDIM))[lane]);
    float wself = di * di;
    float ax = hv.x * wself;
    float ay = hv.y * wself;

    int rs = __builtin_amdgcn_readfirstlane(row_ptr[node]);
    int re = __builtin_amdgcn_readfirstlane(row_ptr[node + 1]);

    int base = rs;
    for (; base + 8 <= re; base += 8) {
        int4 E0 = edges[base + 0];
        int4 E1 = edges[base + 1];
        int4 E2 = edges[base + 2];
        int4 E3 = edges[base + 3];
        int4 E4 = edges[base + 4];
        int4 E5 = edges[base + 5];
        int4 E6 = edges[base + 6];
        int4 E7 = edges[base + 7];
        unsigned u0 = ((const unsigned*)(H + (size_t)E0.x * HDIM))[lane];
        unsigned u1 = ((const unsigned*)(H + (size_t)E1.x * HDIM))[lane];
        unsigned u2 = ((const unsigned*)(H + (size_t)E2.x * HDIM))[lane];
        unsigned u3 = ((const unsigned*)(H + (size_t)E3.x * HDIM))[lane];
        unsigned u4 = ((const unsigned*)(H + (size_t)E4.x * HDIM))[lane];
        unsigned u5 = ((const unsigned*)(H + (size_t)E5.x * HDIM))[lane];
        unsigned u6 = ((const unsigned*)(H + (size_t)E6.x * HDIM))[lane];
        unsigned u7 = ((const unsigned*)(H + (size_t)E7.x * HDIM))[lane];
        float2 v0 = unpack2(u0), v1 = unpack2(u1), v2 = unpack2(u2), v3 = unpack2(u3);
        float2 v4 = unpack2(u4), v5 = unpack2(u5), v6 = unpack2(u6), v7 = unpack2(u7);
        float w0 = __int_as_float(E0.y), w1 = __int_as_float(E1.y);
        float w2 = __int_as_float(E2.y), w3 = __int_as_float(E3.y);
        float w4 = __int_as_float(E4.y), w5 = __int_as_float(E5.y);
        float w6 = __int_as_float(E6.y), w7 = __int_as_float(E7.y);
        ax = fmaf(v0.x, w0, ax); ay = fmaf(v0.y, w0, ay);
        ax = fmaf(v1.x, w1, ax); ay = fmaf(v1.y, w1, ay);
        ax = fmaf(v2.x, w2, ax); ay = fmaf(v2.y, w2, ay);
        ax = fmaf(v3.x, w3, ax); ay = fmaf(v3.y, w3, ay);
        ax = fmaf(v4.x, w4, ax); ay = fmaf(v4.y, w4, ay);
        ax = fmaf(v5.x, w5, ax); ay = fmaf(v5.y, w5, ay);
        ax = fmaf(v6.x, w6, ax); ay = fmaf(v6.y, w6, ay);
        ax = fmaf(v7.x, w7, ax); ay = fmaf(v7.y, w7, ay);
    }
    if (base < re) {                       // clamped tail (1-7 edges)
        int nrem = re - base, m = nrem - 1;
        int4 E0 = edges[base];
        int4 E1 = edges[base + (1 < nrem ? 1 : m)];
        int4 E2 = edges[base + (2 < nrem ? 2 : m)];
        int4 E3 = edges[base + (3 < nrem ? 3 : m)];
        int4 E4 = edges[base + (4 < nrem ? 4 : m)];
        int4 E5 = edges[base + (5 < nrem ? 5 : m)];
        int4 E6 = edges[base + (6 < nrem ? 6 : m)];
        unsigned u0 = ((const unsigned*)(H + (size_t)E0.x * HDIM))[lane];
        unsigned u1 = ((const unsigned*)(H + (size_t)E1.x * HDIM))[lane];
        unsigned u2 = ((const unsigned*)(H + (size_t)E2.x * HDIM))[lane];
        unsigned u3 = ((const unsigned*)(H + (size_t)E3.x * HDIM))[lane];
        unsigned u4 = ((const unsigned*)(H + (size_t)E4.x * HDIM))[lane];
        unsigned u5 = ((const unsigned*)(H + (size_t)E5.x * HDIM))[lane];
        unsigned u6 = ((const unsigned*)(H + (size_t)E6.x * HDIM))[lane];
        float2 v0 = unpack2(u0), v1 = unpack2(u1), v2 = unpack2(u2), v3 = unpack2(u3);
        float2 v4 = unpack2(u4), v5 = unpack2(u5), v6 = unpack2(u6);
        float w0 = __int_as_float(E0.y);
        float w1 = 1 < nrem ? __int_as_float(E1.y) : 0.f;
        float w2 = 2 < nrem ? __int_as_float(E2.y) : 0.f;
        float w3 = 3 < nrem ? __int_as_float(E3.y) : 0.f;
        float w4 = 4 < nrem ? __int_as_float(E4.y) : 0.f;
        float w5 = 5 < nrem ? __int_as_float(E5.y) : 0.f;
        float w6 = 6 < nrem ? __int_as_float(E6.y) : 0.f;
        ax = fmaf(v0.x, w0, ax); ay = fmaf(v0.y, w0, ay);
        ax = fmaf(v1.x, w1, ax); ay = fmaf(v1.y, w1, ay);
        ax = fmaf(v2.x, w2, ax); ay = fmaf(v2.y, w2, ay);
        ax = fmaf(v3.x, w3, ax); ay = fmaf(v3.y, w3, ay);
        ax = fmaf(v4.x, w4, ax); ay = fmaf(v4.y, w4, ay);
        ax = fmaf(v5.x, w5, ax); ay = fmaf(v5.y, w5, ay);
        ax = fmaf(v6.x, w6, ax); ay = fmaf(v6.y, w6, ay);
    }

    float ox = fmaxf(ax + bias[lane * 2],     0.0f);
    float oy = fmaxf(ay + bias[lane * 2 + 1], 0.0f);
    if (PACK) {
        _Float16 hx = (_Float16)ox, hy = (_Float16)oy;
        _Float16 lx = (_Float16)(ox - (float)hx), ly = (_Float16)(oy - (float)hy);
        union { _Float16 h[2]; unsigned u; } ph, pl;
        ph.h[0] = hx; ph.h[1] = hy;
        pl.h[0] = lx; pl.h[1] = ly;
        ((unsigned*)(outHi + (size_t)node * HDIM))[lane] = ph.u;
        ((unsigned*)(outLo + (size_t)node * HDIM))[lane] = pl.u;
    } else {
        ((unsigned*)(outHi + (size_t)node * HDIM))[lane] = pack2(ox, oy);
    }
}

// ---------------- layer-3 pooled aggregation: linear edge sweep ------------
// Single-graph 64-edge chunks (record.z at both ends equal): 16-wide
// clamp-free groups (16 gathers in flight), ONE flush. Boundary chunks
// walk per-edge using record.z.
__global__ __launch_bounds__(256) void k_sweep3(
        const _Float16* __restrict__ H, const int4* __restrict__ edges,
        const float* __restrict__ dinv,
        const int* __restrict__ bt0, const int* __restrict__ bt1,
        int goff0, int nnodes, int nside, int nedges,
        float* __restrict__ pool) {
    int lane = threadIdx.x & 63;
    int wid = blockIdx.x * 4 + (threadIdx.x >> 6);
    int ewaves = (nedges + 63) >> 6;

    if (wid < ewaves) {
        int e0 = wid << 6;
        int e1 = e0 + 64; if (e1 > nedges) e1 = nedges;
        int gfirst = __builtin_amdgcn_readfirstlane(edges[e0].z);
        int glast  = __builtin_amdgcn_readfirstlane(edges[e1 - 1].z);
        float ax = 0.f, ay = 0.f;

        if (gfirst == glast) {
            int base = e0;
            for (; base + 16 <= e1; base += 16) {
                unsigned u[16];
                float w[16];
#pragma unroll
                for (int j = 0; j < 16; j += 4) {
                    int4 Ea = edges[base + j + 0];
                    int4 Eb = edges[base + j + 1];
                    int4 Ec = edges[base + j + 2];
                    int4 Ed = edges[base + j + 3];
                    u[j + 0] = ((const unsigned*)(H + (size_t)Ea.x * HDIM))[lane];
                    u[j + 1] = ((const unsigned*)(H + (size_t)Eb.x * HDIM))[lane];
                    u[j + 2] = ((const unsigned*)(H + (size_t)Ec.x * HDIM))[lane];
                    u[j + 3] = ((const unsigned*)(H + (size_t)Ed.x * HDIM))[lane];
                    w[j + 0] = __int_as_float(Ea.y);
                    w[j + 1] = __int_as_float(Eb.y);
                    w[j + 2] = __int_as_float(Ec.y);
                    w[j + 3] = __int_as_float(Ed.y);
                }
#pragma unroll
                for (int j = 0; j < 16; j++) {
                    float2 v = unpack2(u[j]);
                    ax = fmaf(v.x, w[j], ax);
                    ay = fmaf(v.y, w[j], ay);
                }
            }
            for (; base + 8 <= e1; base += 8) {
#pragma unroll
                for (int j = 0; j < 8; j++) {
                    int4 E = edges[base + j];
                    float2 v = unpack2(((const unsigned*)(H + (size_t)E.x * HDIM))[lane]);
                    float wj = __int_as_float(E.y);
                    ax = fmaf(v.x, wj, ax);
                    ay = fmaf(v.y, wj, ay);
                }
            }
            for (; base < e1; base++) {
                int4 E = edges[base];
                float2 v = unpack2(((const unsigned*)(H + (size_t)E.x * HDIM))[lane]);
                float wj = __int_as_float(E.y);
                ax = fmaf(v.x, wj, ax);
                ay = fmaf(v.y, wj, ay);
            }
            float* p = pool + (size_t)gfirst * HDIM + lane * 2;
            atomicAdd(p, ax); atomicAdd(p + 1, ay);
        } else {
            int gcur = gfirst;
            for (int e = e0; e < e1; e++) {
                int4 E = edges[e];
                int g = __builtin_amdgcn_readfirstlane(E.z);
                if (g != gcur) {
                    float* p = pool + (size_t)gcur * HDIM + lane * 2;
                    atomicAdd(p, ax); atomicAdd(p + 1, ay);
                    ax = 0.f; ay = 0.f;
                    gcur = g;
                }
                float w = __int_as_float(E.y);
                float2 v = unpack2(((const unsigned*)(H + (size_t)E.x * HDIM))[lane]);
                ax = fmaf(v.x, w, ax);
                ay = fmaf(v.y, w, ay);
            }
            float* p = pool + (size_t)gcur * HDIM + lane * 2;
            atomicAdd(p, ax); atomicAdd(p + 1, ay);
        }
    } else {
        // self-loop streaming sweep
        int wid2 = wid - ewaves;
        int n0 = wid2 << 6;
        if (n0 >= nnodes) return;
        int n1 = n0 + 64; if (n1 > nnodes) n1 = nnodes;
        float ax = 0.f, ay = 0.f;
        int gcur = (n0 < nside) ? bt0[n0] + goff0 : bt1[n0 - nside] + NGRAPH;
        gcur = __builtin_amdgcn_readfirstlane(gcur);
        for (int n = n0; n < n1; n++) {
            int g = (n < nside) ? bt0[n] + goff0 : bt1[n - nside] + NGRAPH;
            g = __builtin_amdgcn_readfirstlane(g);
            float dn = dinv[n];
            float w = dn * dn;
            float2 v = unpack2(((const unsigned*)(H + (size_t)n * HDIM))[lane]);
            if (g != gcur) {
                float* p = pool + (size_t)gcur * HDIM + lane * 2;
                atomicAdd(p, ax); atomicAdd(p + 1, ay);
                ax = 0.f; ay = 0.f;
                gcur = g;
            }
            ax = fmaf(v.x, w, ax);
            ay = fmaf(v.y, w, ay);
        }
        float* p = pool + (size_t)gcur * HDIM + lane * 2;
        atomicAdd(p, ax); atomicAdd(p + 1, ay);
    }
}

extern "C" void kernel_launch(void* const* d_in, const int* in_sizes, int n_in,
                              void* d_out, int out_size, void* d_ws, size_t ws_size,
                              hipStream_t stream) {
    (void)in_sizes; (void)n_in; (void)out_size;

    const float* x[2]  = {(const float*)d_in[0], (const float*)d_in[1]};
    const int*   ei[2] = {(const int*)d_in[2], (const int*)d_in[3]};
    const int*   bt[2] = {(const int*)d_in[4], (const int*)d_in[5]};
    const float* W1  = (const float*)d_in[6];  const float* b1  = (const float*)d_in[7];
    const float* W2  = (const float*)d_in[8];  const float* b2  = (const float*)d_in[9];
    const float* W3  = (const float*)d_in[10]; const float* b3  = (const float*)d_in[11];
    const float* Wc1 = (const float*)d_in[12]; const float* bc1 = (const float*)d_in[13];
    const float* Wc2 = (const float*)d_in[14]; const float* bc2 = (const float*)d_in[15];
    const float* Wc3 = (const float*)d_in[16]; const float* bc3 = (const float*)d_in[17];
    float* out = (float*)d_out;

    const bool batched = ws_size >= 120ull * 1000 * 1000;
    const int NN = batched ? 2 * N_NODES : N_NODES;
    const int NE = batched ? 2 * E_EDGES : E_EDGES;

    char* ws = (char*)d_ws;
    size_t off = 0;
    auto carve = [&](size_t bytes) -> char* {
        char* p = ws + off;
        off += (bytes + 255) & ~(size_t)255;
        return p;
    };

    int*   edge_cnt = (int*)  carve((size_t)NN * 4);
    int*   cursor   = (int*)  carve((size_t)NN * 4);
    float* pool_s   = (float*)carve((size_t)2 * NGRAPH * HDIM * 4);
    float* cnt_g    = (float*)carve((size_t)2 * NGRAPH * 4);
    float* dinv     = (float*)carve((size_t)NN * 4);
    int*   row_ptr  = (int*)  carve((size_t)(NN + 1) * 4);
    int4*  edges    = (int4*) carve((size_t)NE * 16);
    int*   blksum   = (int*)  carve(1024 * 4);
    _Float16* wt    = (_Float16*)carve(4 * 128 * 128 * 2);
    _Float16* hS    = (_Float16*)carve((size_t)NN * HDIM * 4);  // hi+lo planes
    _Float16* hA    = (_Float16*)carve((size_t)NN * HDIM * 2);  // f16 gather plane
    float* zcat     = (float*)carve((size_t)NGRAPH * 2 * HDIM * 4);
    float* z1       = (float*)carve((size_t)NGRAPH * 4 * HDIM * 4);
    float* z2       = (float*)carve((size_t)NGRAPH * 2 * HDIM * 4);

    _Float16* w1hi = wt;
    _Float16* w1lo = wt + 128 * 128;
    _Float16* w2hi = wt + 2 * 128 * 128;
    _Float16* w2lo = wt + 3 * 128 * 128;
    _Float16* hShi = hS;
    _Float16* hSlo = hS + (size_t)NN * HDIM;

    const int gblk = (NN + 127) / 128;
    size_t zero_all = (size_t)((char*)cnt_g + 2 * NGRAPH * 4 - (char*)edge_cnt);
    size_t zero_cnt = (size_t)((char*)pool_s - (char*)edge_cnt);

    if (batched) {
        const int nscan = (2 * N_NODES + 511) / 512;
        const int ablk  = (2 * N_NODES + 3) / 4;
        const int swaves = ((2 * E_EDGES + 63) >> 6) + ((2 * N_NODES + 63) >> 6);
        const int sblk = (swaves + 3) / 4;

        hipMemsetAsync(edge_cnt, 0, zero_all, stream);
        k_hist<<<1024, 256, 0, stream>>>(ei[0] + E_EDGES, ei[1] + E_EDGES,
                                         2 * E_EDGES, N_NODES, edge_cnt,
                                         W1, W2, w1hi, w1lo, w2hi, w2lo);
        k_scan_a<<<nscan, 512, 0, stream>>>(edge_cnt, row_ptr, blksum, dinv,
                                            bt[0], bt[1], 0, 2 * N_NODES, N_NODES, cnt_g);
        k_scan_b<<<1, 512, 0, stream>>>(blksum, nscan);
        k_scan_c<<<nscan, 512, 0, stream>>>(row_ptr, blksum, cursor, 2 * N_NODES, 2 * E_EDGES);
        k_fill<<<1024, 256, 0, stream>>>(ei[0], ei[1], ei[0] + E_EDGES, ei[1] + E_EDGES,
                                         2 * E_EDGES, N_NODES, 0, bt[0], bt[1],
                                         cursor, dinv, edges);

        k_gemm_split<1><<<gblk, 256, 0, stream>>>(x[0], x[1], N_NODES,
                                                  nullptr, nullptr, w1hi, w1lo, hA, 2 * N_NODES);
        k_agg<1><<<ablk, 256, 0, stream>>>(hA, dinv, row_ptr, edges, b1,
                                           hShi, hSlo, 2 * N_NODES);
        k_gemm_split<0><<<gblk, 256, 0, stream>>>(nullptr, nullptr, 0,
                                                  hShi, hSlo, w2hi, w2lo, hA, 2 * N_NODES);
        k_agg<0><<<ablk, 256, 0, stream>>>(hA, dinv, row_ptr, edges, b2,
                                           hShi, nullptr, 2 * N_NODES);
        k_sweep3<<<sblk, 256, 0, stream>>>(hShi, edges, dinv, bt[0], bt[1],
                                           0, 2 * N_NODES, N_NODES, 2 * E_EDGES, pool_s);
    } else {
        const int nscan = (N_NODES + 511) / 512;
        const int ablk  = (N_NODES + 3) / 4;
        const int swaves = ((E_EDGES + 63) >> 6) + ((N_NODES + 63) >> 6);
        const int sblk = (swaves + 3) / 4;

        for (int s = 0; s < 2; ++s) {
            const int* esrc = ei[s];
            const int* edst = ei[s] + E_EDGES;
            int goff = s * NGRAPH;

            hipMemsetAsync(edge_cnt, 0, s == 0 ? zero_all : zero_cnt, stream);
            k_hist<<<512, 256, 0, stream>>>(edst, edst, E_EDGES, 0, edge_cnt,
                                            W1, W2, w1hi, w1lo, w2hi, w2lo);
            k_scan_a<<<nscan, 512, 0, stream>>>(edge_cnt, row_ptr, blksum, dinv,
                                                bt[s], bt[s], goff, N_NODES, N_NODES, cnt_g);
            k_scan_b<<<1, 512, 0, stream>>>(blksum, nscan);
            k_scan_c<<<nscan, 512, 0, stream>>>(row_ptr, blksum, cursor, N_NODES, E_EDGES);
            k_fill<<<512, 256, 0, stream>>>(esrc, esrc, edst, edst, E_EDGES, 0, goff,
                                            bt[s], bt[s], cursor, dinv, edges);

            k_gemm_split<1><<<gblk, 256, 0, stream>>>(x[s], x[s], N_NODES,
                                                      nullptr, nullptr, w1hi, w1lo, hA, N_NODES);
            k_agg<1><<<ablk, 256, 0, stream>>>(hA, dinv, row_ptr, edges, b1,
                                               hShi, hSlo, N_NODES);
            k_gemm_split<0><<<gblk, 256, 0, stream>>>(nullptr, nullptr, 0,
                                                      hShi, hSlo, w2hi, w2lo, hA, N_NODES);
            k_agg<0><<<ablk, 256, 0, stream>>>(hA, dinv, row_ptr, edges, b2,
                                               hShi, nullptr, N_NODES);
            k_sweep3<<<sblk, 256, 0, stream>>>(hShi, edges, dinv, bt[s], bt[s],
                                               goff, N_NODES, N_NODES, E_EDGES, pool_s);
        }
    }

    k_gemm_pool<<<dim3(NGRAPH / 64, 2, 2), 256, 0, stream>>>(pool_s, cnt_g, W3, b3, zcat);

    k_gemm<<<dim3(NGRAPH / 64, (4 * HDIM) / 64), 256, 0, stream>>>(zcat, Wc1, bc1, z1, NGRAPH, 4 * HDIM, 2 * HDIM, 4 * HDIM, 1);
    k_gemm<<<dim3(NGRAPH / 64, (2 * HDIM) / 64), 256, 0, stream>>>(z1, Wc2, bc2, z2, NGRAPH, 2 * HDIM, 4 * HDIM, 2 * HDIM, 1);
    k_gemm<<<dim3(NGRAPH / 64, 1), 256, 0, stream>>>(z2, Wc3, bc3, out, NGRAPH, OUTC, 2 * HDIM, OUTC, 0);
}